// Round 1
// baseline (414.160 us; speedup 1.0000x reference)
//
#include <hip/hip_runtime.h>
#include <math.h>

// NanoRAG: cosine-sim retrieval + top-8 + softmax fusion.
// K0: normalize queries -> ws.qn
// K1: fp32 register-tiled Qn·D^T (64q x 128d per block), inline doc-norm,
//     per-block top-8 per query -> ws.partial
// K2: merge 2048 partial lists -> final top-8, softmax, gather+fuse -> d_out
//
// d_out layout (all read as fp32 by harness): fused[64*384], scores[64*8], idx[64*8]

#define EMBED 384
#define NDOCS 262144
#define BATCH 64
#define TOPK 8
#define DBLK 128
#define KBLK 32
#define NBLK (NDOCS / DBLK)   // 2048
#define EPSN 1e-8f

#define QS_STRIDE 72    // 64 + 8 pad (words)
#define DS_STRIDE 132   // 128 + 4 pad (words)
#define SC_STRIDE 132

// register-resident sorted top-8 insertion (all indices compile-time)
#define INS8(s_, i_) do {                                                     \
    if ((s_) > ts[7] || ((s_) == ts[7] && (i_) < ti[7])) {                    \
        ts[7] = (s_); ti[7] = (i_);                                           \
        _Pragma("unroll")                                                     \
        for (int r_ = 7; r_ > 0; --r_) {                                      \
            bool sw_ = (ts[r_] > ts[r_-1]) ||                                 \
                       (ts[r_] == ts[r_-1] && ti[r_] < ti[r_-1]);             \
            float a_ = ts[r_-1]; int b_ = ti[r_-1];                           \
            ts[r_-1] = sw_ ? ts[r_] : a_;  ti[r_-1] = sw_ ? ti[r_] : b_;      \
            ts[r_]   = sw_ ? a_ : ts[r_];  ti[r_]   = sw_ ? b_ : ti[r_];      \
        }                                                                     \
    }                                                                         \
} while (0)

__global__ void qnorm_kernel(const float* __restrict__ q, float* __restrict__ qn) {
    int lane = threadIdx.x & 63;
    int wave = threadIdx.x >> 6;
    for (int row = wave; row < BATCH; row += 4) {
        float v[6];
        float s = 0.f;
#pragma unroll
        for (int i = 0; i < 6; ++i) {
            v[i] = q[row * EMBED + lane + 64 * i];
            s += v[i] * v[i];
        }
#pragma unroll
        for (int off = 32; off > 0; off >>= 1) s += __shfl_xor(s, off);
        float r = 1.0f / (sqrtf(s) + EPSN);
#pragma unroll
        for (int i = 0; i < 6; ++i) qn[row * EMBED + lane + 64 * i] = v[i] * r;
    }
}

__global__ __launch_bounds__(256) void score_topk_kernel(
        const float* __restrict__ docs, const float* __restrict__ qn,
        float* __restrict__ pscore, int* __restrict__ pidx) {
    // smem: during K-loop holds Qs_t[32][72] + Ds_t[32][132] (6528 floats);
    // afterwards reused as score tile s[64][132] (8448 floats).
    __shared__ float smem[BATCH * SC_STRIDE];
    __shared__ float rnorm[DBLK];
    float* Qs = smem;
    float* Ds = smem + KBLK * QS_STRIDE;

    const int tid = threadIdx.x;
    const int d0 = blockIdx.x * DBLK;
    const int qb = (tid >> 5) << 3;   // 8 queries per thread
    const int db = (tid & 31) << 2;   // 4 docs per thread

    float acc[8][4];
#pragma unroll
    for (int i = 0; i < 8; ++i)
#pragma unroll
        for (int j = 0; j < 4; ++j) acc[i][j] = 0.f;
    float nacc = 0.f;   // doc-norm partial (threads 0..127, doc = tid)

    for (int k0 = 0; k0 < EMBED; k0 += KBLK) {
        // stage Q tile transposed: Qs_t[k][q]
#pragma unroll
        for (int i = 0; i < 2; ++i) {
            int fidx = tid + 256 * i;
            int qq = fidx >> 3, quad = fidx & 7;
            float4 v = *(const float4*)(qn + qq * EMBED + k0 + quad * 4);
            int kk = quad << 2;
            Qs[(kk + 0) * QS_STRIDE + qq] = v.x;
            Qs[(kk + 1) * QS_STRIDE + qq] = v.y;
            Qs[(kk + 2) * QS_STRIDE + qq] = v.z;
            Qs[(kk + 3) * QS_STRIDE + qq] = v.w;
        }
        // stage D tile transposed: Ds_t[k][d]
#pragma unroll
        for (int i = 0; i < 4; ++i) {
            int fidx = tid + 256 * i;
            int dd = fidx >> 3, quad = fidx & 7;
            float4 v = *(const float4*)(docs + (size_t)(d0 + dd) * EMBED + k0 + quad * 4);
            int kk = quad << 2;
            Ds[(kk + 0) * DS_STRIDE + dd] = v.x;
            Ds[(kk + 1) * DS_STRIDE + dd] = v.y;
            Ds[(kk + 2) * DS_STRIDE + dd] = v.z;
            Ds[(kk + 3) * DS_STRIDE + dd] = v.w;
        }
        __syncthreads();
        // deterministic per-doc sumsq from staged tile (no atomics)
        if (tid < DBLK) {
            float s = 0.f;
#pragma unroll
            for (int k = 0; k < KBLK; ++k) {
                float v = Ds[k * DS_STRIDE + tid];
                s += v * v;
            }
            nacc += s;
        }
        // outer-product compute: per k read 2+1 contiguous float4 fragments
#pragma unroll 4
        for (int k = 0; k < KBLK; ++k) {
            float4 a0 = *(const float4*)&Qs[k * QS_STRIDE + qb];
            float4 a1 = *(const float4*)&Qs[k * QS_STRIDE + qb + 4];
            float4 bv = *(const float4*)&Ds[k * DS_STRIDE + db];
            float av[8] = {a0.x, a0.y, a0.z, a0.w, a1.x, a1.y, a1.z, a1.w};
            float bb[4] = {bv.x, bv.y, bv.z, bv.w};
#pragma unroll
            for (int i = 0; i < 8; ++i)
#pragma unroll
                for (int j = 0; j < 4; ++j)
                    acc[i][j] = fmaf(av[i], bb[j], acc[i][j]);
        }
        __syncthreads();
    }

    if (tid < DBLK) rnorm[tid] = 1.0f / (sqrtf(nacc) + EPSN);
    __syncthreads();

    // scale by 1/(||d||+eps) and park score tile in smem (q-major, padded)
    float rd0 = rnorm[db + 0], rd1 = rnorm[db + 1];
    float rd2 = rnorm[db + 2], rd3 = rnorm[db + 3];
#pragma unroll
    for (int i = 0; i < 8; ++i) {
        float4 w = make_float4(acc[i][0] * rd0, acc[i][1] * rd1,
                               acc[i][2] * rd2, acc[i][3] * rd3);
        *(float4*)&smem[(qb + i) * SC_STRIDE + db] = w;
    }
    __syncthreads();

    // per-query top-8 over this block's 128 docs (staggered scan: bank-clean)
    if (tid < BATCH) {
        const int q = tid;
        float ts[8]; int ti[8];
#pragma unroll
        for (int r = 0; r < 8; ++r) { ts[r] = -3.402823466e38f; ti[r] = 0x7fffffff; }
        for (int ii = 0; ii < DBLK; ++ii) {
            int d = (ii + q) & (DBLK - 1);
            float s = smem[q * SC_STRIDE + d];
            int gi = d0 + d;
            INS8(s, gi);
        }
#pragma unroll
        for (int r = 0; r < TOPK; ++r) {
            size_t o = ((size_t)blockIdx.x * BATCH + q) * TOPK + r;
            pscore[o] = ts[r];
            pidx[o] = ti[r];
        }
    }
}

__global__ __launch_bounds__(256) void merge_fuse_kernel(
        const float* __restrict__ docs, const float* __restrict__ pscore,
        const int* __restrict__ pidx, float* __restrict__ out) {
    const int q = blockIdx.x;
    const int tid = threadIdx.x;
    __shared__ float ls[2048];
    __shared__ int   li[2048];
    __shared__ float ls2[512];
    __shared__ int   li2[512];
    __shared__ int   fi[TOPK];
    __shared__ float wr[TOPK];

    float ts[8]; int ti[8];
#pragma unroll
    for (int r = 0; r < 8; ++r) { ts[r] = -3.402823466e38f; ti[r] = 0x7fffffff; }

    // level 0: each thread reduces 64 of the 16384 candidates
    for (int c = 0; c < 64; ++c) {
        int cand = tid * 64 + c;
        int blk = cand >> 3, r = cand & 7;
        size_t o = ((size_t)blk * BATCH + q) * TOPK + r;
        float s = pscore[o];
        int gi = pidx[o];
        INS8(s, gi);
    }
#pragma unroll
    for (int r = 0; r < 8; ++r) { ls[tid * 8 + r] = ts[r]; li[tid * 8 + r] = ti[r]; }
    __syncthreads();

    // level 1: 64 threads reduce 2048 -> 512
    if (tid < 64) {
#pragma unroll
        for (int r = 0; r < 8; ++r) { ts[r] = -3.402823466e38f; ti[r] = 0x7fffffff; }
        for (int c = 0; c < 32; ++c) {
            int e = tid * 32 + c;
            float s = ls[e]; int gi = li[e];
            INS8(s, gi);
        }
#pragma unroll
        for (int r = 0; r < 8; ++r) { ls2[tid * 8 + r] = ts[r]; li2[tid * 8 + r] = ti[r]; }
    }
    __syncthreads();

    // level 2: thread 0 reduces 512 -> final 8; softmax; emit scores+idx
    if (tid == 0) {
#pragma unroll
        for (int r = 0; r < 8; ++r) { ts[r] = -3.402823466e38f; ti[r] = 0x7fffffff; }
        for (int e = 0; e < 512; ++e) {
            float s = ls2[e]; int gi = li2[e];
            INS8(s, gi);
        }
        float m = ts[0];  // list sorted desc
        float w[8]; float sum = 0.f;
#pragma unroll
        for (int r = 0; r < 8; ++r) { w[r] = expf(ts[r] - m); sum += w[r]; }
        float rs = 1.0f / sum;
#pragma unroll
        for (int r = 0; r < 8; ++r) {
            fi[r] = ti[r];
            wr[r] = w[r] * rs;
            out[BATCH * EMBED + q * TOPK + r] = ts[r];
            out[BATCH * EMBED + BATCH * TOPK + q * TOPK + r] = (float)ti[r];
        }
    }
    __syncthreads();

    // per-retrieved-doc norm, folded into weight: wr[r] /= (||d||+eps)
    int lane = tid & 63, wave = tid >> 6;
    for (int r = wave; r < TOPK; r += 4) {
        const float* dp = docs + (size_t)fi[r] * EMBED;
        float s = 0.f;
#pragma unroll
        for (int i = 0; i < 6; ++i) { float v = dp[lane + 64 * i]; s += v * v; }
#pragma unroll
        for (int off = 32; off > 0; off >>= 1) s += __shfl_xor(s, off);
        if (lane == 0) wr[r] = wr[r] / (sqrtf(s) + EPSN);
    }
    __syncthreads();

    // fused[q][dim] = sum_r wr[r] * docs[fi[r]][dim]
    for (int dim = tid; dim < EMBED; dim += 256) {
        float a = 0.f;
#pragma unroll
        for (int r = 0; r < 8; ++r)
            a += wr[r] * docs[(size_t)fi[r] * EMBED + dim];
        out[q * EMBED + dim] = a;
    }
}

extern "C" void kernel_launch(void* const* d_in, const int* in_sizes, int n_in,
                              void* d_out, int out_size, void* d_ws, size_t ws_size,
                              hipStream_t stream) {
    const float* query = (const float*)d_in[0];
    const float* docs  = (const float*)d_in[1];
    float* out = (float*)d_out;

    char* ws = (char*)d_ws;
    float* qn     = (float*)ws;                                   // 98304 B
    float* pscore = (float*)(ws + 98304);                         // 4 MiB
    int*   pidx   = (int*)(ws + 98304 + (size_t)NBLK * BATCH * TOPK * 4);

    qnorm_kernel<<<1, 256, 0, stream>>>(query, qn);
    score_topk_kernel<<<NBLK, 256, 0, stream>>>(docs, qn, pscore, pidx);
    merge_fuse_kernel<<<BATCH, 256, 0, stream>>>(docs, pscore, pidx, out);
}

// Round 2
// 343.546 us; speedup vs baseline: 1.2055x; 1.2055x over previous
//
#include <hip/hip_runtime.h>
#include <math.h>

// NanoRAG: cosine-sim retrieval + top-8 + softmax fusion.
// K0: normalize queries, split into bf16 hi/lo -> ws.qh/ws.ql
// K1: split-bf16 MFMA GEMM (3-product Markidis), docs streamed global->reg
//     (B-fragment layout == row-major docs), inline doc-norm via shfl,
//     per-block (128 docs) top-8 per query -> ws.partial
// K2: merge 2048 partial lists -> final top-8, softmax, gather+fuse -> d_out
//
// d_out layout (fp32): fused[64*384], scores[64*8], idx[64*8]

#define EMBED 384
#define NDOCS 262144
#define BATCH 64
#define TOPK 8
#define DBLK 128
#define NBLK (NDOCS / DBLK)   // 2048
#define EPSN 1e-8f
#define SC_STRIDE 132

typedef __attribute__((ext_vector_type(8))) short bf16x8;
typedef __attribute__((ext_vector_type(4))) float f32x4;

// register-resident sorted top-8 insertion (all indices compile-time)
#define INS8(s_, i_) do {                                                     \
    if ((s_) > ts[7] || ((s_) == ts[7] && (i_) < ti[7])) {                    \
        ts[7] = (s_); ti[7] = (i_);                                           \
        _Pragma("unroll")                                                     \
        for (int r_ = 7; r_ > 0; --r_) {                                      \
            bool sw_ = (ts[r_] > ts[r_-1]) ||                                 \
                       (ts[r_] == ts[r_-1] && ti[r_] < ti[r_-1]);             \
            float a_ = ts[r_-1]; int b_ = ti[r_-1];                           \
            ts[r_-1] = sw_ ? ts[r_] : a_;  ti[r_-1] = sw_ ? ti[r_] : b_;      \
            ts[r_]   = sw_ ? a_ : ts[r_];  ti[r_]   = sw_ ? b_ : ti[r_];      \
        }                                                                     \
    }                                                                         \
} while (0)

// RNE split of fp32 into bf16 high + bf16 low: f ~= hi + lo, |err| <= 2^-18|f|
__device__ __forceinline__ void split8(float4 f0, float4 f1, bf16x8& bh, bf16x8& bl) {
    float f[8] = {f0.x, f0.y, f0.z, f0.w, f1.x, f1.y, f1.z, f1.w};
#pragma unroll
    for (int i = 0; i < 8; ++i) {
        unsigned u = __float_as_uint(f[i]);
        unsigned h = (u + 0x7fffu + ((u >> 16) & 1u)) >> 16;
        float fh = __uint_as_float(h << 16);
        float r = f[i] - fh;                      // exact (Sterbenz)
        unsigned v = __float_as_uint(r);
        unsigned lo = (v + 0x7fffu + ((v >> 16) & 1u)) >> 16;
        bh[i] = (short)h;
        bl[i] = (short)lo;
    }
}

__global__ void qprep_kernel(const float* __restrict__ q,
                             unsigned short* __restrict__ qh,
                             unsigned short* __restrict__ ql) {
    const int row = blockIdx.x;     // 64 blocks
    const int lane = threadIdx.x;   // 64 threads
    float v[6];
    float s = 0.f;
#pragma unroll
    for (int i = 0; i < 6; ++i) {
        v[i] = q[row * EMBED + lane + 64 * i];
        s = fmaf(v[i], v[i], s);
    }
#pragma unroll
    for (int off = 32; off > 0; off >>= 1) s += __shfl_xor(s, off);
    float rinv = 1.0f / (sqrtf(s) + EPSN);
#pragma unroll
    for (int i = 0; i < 6; ++i) {
        float f = v[i] * rinv;
        unsigned u = __float_as_uint(f);
        unsigned h = (u + 0x7fffu + ((u >> 16) & 1u)) >> 16;
        float fh = __uint_as_float(h << 16);
        float r = f - fh;
        unsigned vv = __float_as_uint(r);
        unsigned lo = (vv + 0x7fffu + ((vv >> 16) & 1u)) >> 16;
        qh[row * EMBED + lane + 64 * i] = (unsigned short)h;
        ql[row * EMBED + lane + 64 * i] = (unsigned short)lo;
    }
}

__global__ __launch_bounds__(256) void score_topk_kernel(
        const float* __restrict__ docs,
        const unsigned short* __restrict__ qh,
        const unsigned short* __restrict__ ql,
        float* __restrict__ pscore, int* __restrict__ pidx) {
    __shared__ float S[BATCH * SC_STRIDE];   // 64 x 132 score tile (33.8 KB)

    const int tid = threadIdx.x;
    const int l = tid & 63;
    const int w = tid >> 6;            // wave 0..3 -> 32-doc column group
    const int rowl = l & 15;           // A row / B col within fragment
    const int koff = (l >> 4) * 8;     // k sub-block
    const int d0 = blockIdx.x * DBLK;

    f32x4 acc[2][4];                   // [strip][mtile]
#pragma unroll
    for (int s = 0; s < 2; ++s)
#pragma unroll
        for (int m = 0; m < 4; ++m) acc[s][m] = (f32x4){0.f, 0.f, 0.f, 0.f};
    float sq[2] = {0.f, 0.f};

    const float* dbase = docs + (size_t)(d0 + w * 32 + rowl) * EMBED + koff;
    const unsigned short* qhb = qh + rowl * EMBED + koff;
    const unsigned short* qlb = ql + rowl * EMBED + koff;

    for (int kb = 0; kb < EMBED / 32; ++kb) {
        const int kk = kb * 32;
        bf16x8 ah[4], al[4];
#pragma unroll
        for (int m = 0; m < 4; ++m) {
            ah[m] = *(const bf16x8*)(qhb + m * (16 * EMBED) + kk);
            al[m] = *(const bf16x8*)(qlb + m * (16 * EMBED) + kk);
        }
#pragma unroll
        for (int s = 0; s < 2; ++s) {
            const float* dp = dbase + s * (16 * EMBED) + kk;
            float4 f0 = *(const float4*)dp;
            float4 f1 = *(const float4*)(dp + 4);
            sq[s] = fmaf(f0.x, f0.x, sq[s]); sq[s] = fmaf(f0.y, f0.y, sq[s]);
            sq[s] = fmaf(f0.z, f0.z, sq[s]); sq[s] = fmaf(f0.w, f0.w, sq[s]);
            sq[s] = fmaf(f1.x, f1.x, sq[s]); sq[s] = fmaf(f1.y, f1.y, sq[s]);
            sq[s] = fmaf(f1.z, f1.z, sq[s]); sq[s] = fmaf(f1.w, f1.w, sq[s]);
            bf16x8 bh, bl;
            split8(f0, f1, bh, bl);
#pragma unroll
            for (int m = 0; m < 4; ++m)
                acc[s][m] = __builtin_amdgcn_mfma_f32_16x16x32_bf16(ah[m], bh, acc[s][m], 0, 0, 0);
#pragma unroll
            for (int m = 0; m < 4; ++m)
                acc[s][m] = __builtin_amdgcn_mfma_f32_16x16x32_bf16(al[m], bh, acc[s][m], 0, 0, 0);
#pragma unroll
            for (int m = 0; m < 4; ++m)
                acc[s][m] = __builtin_amdgcn_mfma_f32_16x16x32_bf16(ah[m], bl, acc[s][m], 0, 0, 0);
        }
    }

    // doc norms: 4 lanes (l, l^16, l^32, l^48) share one doc row
#pragma unroll
    for (int s = 0; s < 2; ++s) {
        float t = sq[s];
        t += __shfl_xor(t, 16);
        t += __shfl_xor(t, 32);
        float rn = 1.0f / (sqrtf(t) + EPSN);
        const int col = w * 32 + s * 16 + rowl;
        const int q0 = (l >> 4) * 4;   // C/D: row=(lane>>4)*4+reg, col=lane&15
#pragma unroll
        for (int m = 0; m < 4; ++m) {
            f32x4 a = acc[s][m];
            S[(m * 16 + q0 + 0) * SC_STRIDE + col] = a[0] * rn;
            S[(m * 16 + q0 + 1) * SC_STRIDE + col] = a[1] * rn;
            S[(m * 16 + q0 + 2) * SC_STRIDE + col] = a[2] * rn;
            S[(m * 16 + q0 + 3) * SC_STRIDE + col] = a[3] * rn;
        }
    }
    __syncthreads();

    // per-query top-8 over this block's 128 docs (staggered scan, 1 wave)
    if (tid < BATCH) {
        const int q = tid;
        float ts[8]; int ti[8];
#pragma unroll
        for (int r = 0; r < 8; ++r) { ts[r] = -3.402823466e38f; ti[r] = 0x7fffffff; }
        for (int ii = 0; ii < DBLK; ++ii) {
            int d = (ii + q) & (DBLK - 1);
            float sc = S[q * SC_STRIDE + d];
            INS8(sc, d0 + d);
        }
#pragma unroll
        for (int r = 0; r < TOPK; ++r) {
            size_t o = ((size_t)blockIdx.x * BATCH + q) * TOPK + r;
            pscore[o] = ts[r];
            pidx[o] = ti[r];
        }
    }
}

__global__ __launch_bounds__(256) void merge_fuse_kernel(
        const float* __restrict__ docs, const float* __restrict__ pscore,
        const int* __restrict__ pidx, float* __restrict__ out) {
    const int q = blockIdx.x;
    const int tid = threadIdx.x;
    __shared__ float ls[2048];
    __shared__ int   li[2048];
    __shared__ float ls2[512];
    __shared__ int   li2[512];
    __shared__ int   fi[TOPK];
    __shared__ float wr[TOPK];

    float ts[8]; int ti[8];
#pragma unroll
    for (int r = 0; r < 8; ++r) { ts[r] = -3.402823466e38f; ti[r] = 0x7fffffff; }

    // level 0: each thread reduces 8 sorted partial lists (vectorized + early skip)
    for (int b8 = 0; b8 < 8; ++b8) {
        int blk = tid * 8 + b8;
        const float* sp = pscore + ((size_t)blk * BATCH + q) * TOPK;
        const int*   ip = pidx   + ((size_t)blk * BATCH + q) * TOPK;
        float4 s0 = *(const float4*)sp;
        if (s0.x < ts[7]) continue;   // sorted desc: nothing can insert
        float4 s1 = *(const float4*)(sp + 4);
        int4 i0 = *(const int4*)ip;
        int4 i1 = *(const int4*)(ip + 4);
        INS8(s0.x, i0.x); INS8(s0.y, i0.y); INS8(s0.z, i0.z); INS8(s0.w, i0.w);
        INS8(s1.x, i1.x); INS8(s1.y, i1.y); INS8(s1.z, i1.z); INS8(s1.w, i1.w);
    }
#pragma unroll
    for (int r = 0; r < 8; ++r) { ls[tid * 8 + r] = ts[r]; li[tid * 8 + r] = ti[r]; }
    __syncthreads();

    // level 1: 64 threads reduce 2048 -> 512
    if (tid < 64) {
#pragma unroll
        for (int r = 0; r < 8; ++r) { ts[r] = -3.402823466e38f; ti[r] = 0x7fffffff; }
        for (int c = 0; c < 32; ++c) {
            int e = tid * 32 + c;
            float s = ls[e]; int gi = li[e];
            INS8(s, gi);
        }
#pragma unroll
        for (int r = 0; r < 8; ++r) { ls2[tid * 8 + r] = ts[r]; li2[tid * 8 + r] = ti[r]; }
    }
    __syncthreads();

    // level 2: thread 0 reduces 512 -> final 8; softmax; emit scores+idx
    if (tid == 0) {
#pragma unroll
        for (int r = 0; r < 8; ++r) { ts[r] = -3.402823466e38f; ti[r] = 0x7fffffff; }
        for (int e = 0; e < 512; ++e) {
            float s = ls2[e]; int gi = li2[e];
            INS8(s, gi);
        }
        float m = ts[0];  // sorted desc
        float w[8]; float sum = 0.f;
#pragma unroll
        for (int r = 0; r < 8; ++r) { w[r] = expf(ts[r] - m); sum += w[r]; }
        float rs = 1.0f / sum;
#pragma unroll
        for (int r = 0; r < 8; ++r) {
            fi[r] = ti[r];
            wr[r] = w[r] * rs;
            out[BATCH * EMBED + q * TOPK + r] = ts[r];
            out[BATCH * EMBED + BATCH * TOPK + q * TOPK + r] = (float)ti[r];
        }
    }
    __syncthreads();

    // fold retrieved-doc norm into weight: wr[r] /= (||d||+eps)
    int lane = tid & 63, wave = tid >> 6;
    for (int r = wave; r < TOPK; r += 4) {
        const float* dp = docs + (size_t)fi[r] * EMBED;
        float s = 0.f;
#pragma unroll
        for (int i = 0; i < 6; ++i) { float v = dp[lane + 64 * i]; s = fmaf(v, v, s); }
#pragma unroll
        for (int off = 32; off > 0; off >>= 1) s += __shfl_xor(s, off);
        if (lane == 0) wr[r] = wr[r] / (sqrtf(s) + EPSN);
    }
    __syncthreads();

    // fused[q][dim] = sum_r wr[r] * docs[fi[r]][dim]
    for (int dim = tid; dim < EMBED; dim += 256) {
        float a = 0.f;
#pragma unroll
        for (int r = 0; r < 8; ++r)
            a += wr[r] * docs[(size_t)fi[r] * EMBED + dim];
        out[q * EMBED + dim] = a;
    }
}

extern "C" void kernel_launch(void* const* d_in, const int* in_sizes, int n_in,
                              void* d_out, int out_size, void* d_ws, size_t ws_size,
                              hipStream_t stream) {
    const float* query = (const float*)d_in[0];
    const float* docs  = (const float*)d_in[1];
    float* out = (float*)d_out;

    char* ws = (char*)d_ws;
    unsigned short* qh = (unsigned short*)ws;                       // 48 KiB
    unsigned short* ql = (unsigned short*)(ws + 49152);             // 48 KiB
    float* pscore = (float*)(ws + 98304);                           // 4 MiB
    int*   pidx   = (int*)(ws + 98304 + (size_t)NBLK * BATCH * TOPK * 4);

    qprep_kernel<<<64, 64, 0, stream>>>(query, qh, ql);
    score_topk_kernel<<<NBLK, 256, 0, stream>>>(docs, qh, ql, pscore, pidx);
    merge_fuse_kernel<<<BATCH, 256, 0, stream>>>(docs, pscore, pidx, out);
}

// Round 3
// 288.107 us; speedup vs baseline: 1.4375x; 1.1924x over previous
//
#include <hip/hip_runtime.h>
#include <math.h>

// NanoRAG: cosine-sim retrieval + top-8 + softmax fusion.
// K0: normalize queries, split into bf16 hi/lo -> ws.qh/ws.ql
// K1: split-bf16 MFMA GEMM (qh*dh + ql*dh + qh*dl), docs streamed
//     global->reg with register double-buffer (prefetch kb+1), inline
//     doc-norm via shfl, 2-wave per-block top-8 -> ws.partial [q][blk][r]
// K2: merge (coalesced) -> final top-8, softmax, gather+fuse -> d_out
//
// d_out layout (fp32): fused[64*384], scores[64*8], idx[64*8]

#define EMBED 384
#define NDOCS 262144
#define BATCH 64
#define TOPK 8
#define DBLK 128
#define NBLK (NDOCS / DBLK)   // 2048
#define EPSN 1e-8f
#define SC_STRIDE 132

typedef __attribute__((ext_vector_type(8))) short bf16x8;
typedef __attribute__((ext_vector_type(4))) float f32x4;

// register-resident sorted top-8 insertion (all indices compile-time)
#define INS8(s_, i_) do {                                                     \
    if ((s_) > ts[7] || ((s_) == ts[7] && (i_) < ti[7])) {                    \
        ts[7] = (s_); ti[7] = (i_);                                           \
        _Pragma("unroll")                                                     \
        for (int r_ = 7; r_ > 0; --r_) {                                      \
            bool sw_ = (ts[r_] > ts[r_-1]) ||                                 \
                       (ts[r_] == ts[r_-1] && ti[r_] < ti[r_-1]);             \
            float a_ = ts[r_-1]; int b_ = ti[r_-1];                           \
            ts[r_-1] = sw_ ? ts[r_] : a_;  ti[r_-1] = sw_ ? ti[r_] : b_;      \
            ts[r_]   = sw_ ? a_ : ts[r_];  ti[r_]   = sw_ ? b_ : ti[r_];      \
        }                                                                     \
    }                                                                         \
} while (0)

// RNE split of fp32 into bf16 high + bf16 low: f ~= hi + lo, |err| <= 2^-18|f|
__device__ __forceinline__ void split8(float4 f0, float4 f1, bf16x8& bh, bf16x8& bl) {
    float f[8] = {f0.x, f0.y, f0.z, f0.w, f1.x, f1.y, f1.z, f1.w};
#pragma unroll
    for (int i = 0; i < 8; ++i) {
        unsigned u = __float_as_uint(f[i]);
        unsigned h = (u + 0x7fffu + ((u >> 16) & 1u)) >> 16;
        float fh = __uint_as_float(h << 16);
        float r = f[i] - fh;                      // exact
        unsigned v = __float_as_uint(r);
        unsigned lo = (v + 0x7fffu + ((v >> 16) & 1u)) >> 16;
        bh[i] = (short)h;
        bl[i] = (short)lo;
    }
}

__device__ __forceinline__ float dot8(float4 f0, float4 f1, float s) {
    s = fmaf(f0.x, f0.x, s); s = fmaf(f0.y, f0.y, s);
    s = fmaf(f0.z, f0.z, s); s = fmaf(f0.w, f0.w, s);
    s = fmaf(f1.x, f1.x, s); s = fmaf(f1.y, f1.y, s);
    s = fmaf(f1.z, f1.z, s); s = fmaf(f1.w, f1.w, s);
    return s;
}

__global__ void qprep_kernel(const float* __restrict__ q,
                             unsigned short* __restrict__ qh,
                             unsigned short* __restrict__ ql) {
    const int row = blockIdx.x;     // 64 blocks
    const int lane = threadIdx.x;   // 64 threads
    float v[6];
    float s = 0.f;
#pragma unroll
    for (int i = 0; i < 6; ++i) {
        v[i] = q[row * EMBED + lane + 64 * i];
        s = fmaf(v[i], v[i], s);
    }
#pragma unroll
    for (int off = 32; off > 0; off >>= 1) s += __shfl_xor(s, off);
    float rinv = 1.0f / (sqrtf(s) + EPSN);
#pragma unroll
    for (int i = 0; i < 6; ++i) {
        float f = v[i] * rinv;
        unsigned u = __float_as_uint(f);
        unsigned h = (u + 0x7fffu + ((u >> 16) & 1u)) >> 16;
        float fh = __uint_as_float(h << 16);
        float r = f - fh;
        unsigned vv = __float_as_uint(r);
        unsigned lo = (vv + 0x7fffu + ((vv >> 16) & 1u)) >> 16;
        qh[row * EMBED + lane + 64 * i] = (unsigned short)h;
        ql[row * EMBED + lane + 64 * i] = (unsigned short)lo;
    }
}

__global__ __launch_bounds__(256, 4) void score_topk_kernel(
        const float* __restrict__ docs,
        const unsigned short* __restrict__ qh,
        const unsigned short* __restrict__ ql,
        float* __restrict__ pscore, int* __restrict__ pidx) {
    __shared__ float S[BATCH * SC_STRIDE];   // 64 x 132 score tile (33.8 KB)

    const int tid = threadIdx.x;
    const int l = tid & 63;
    const int w = tid >> 6;            // wave 0..3 -> 32-doc column group
    const int rowl = l & 15;           // A row / B col within fragment
    const int koff = (l >> 4) * 8;     // k sub-block
    const int d0 = blockIdx.x * DBLK;

    f32x4 acc[2][4];                   // [strip][mtile]
#pragma unroll
    for (int s = 0; s < 2; ++s)
#pragma unroll
        for (int m = 0; m < 4; ++m) acc[s][m] = (f32x4){0.f, 0.f, 0.f, 0.f};
    float sq0 = 0.f, sq1 = 0.f;

    const float* dp0 = docs + (size_t)(d0 + w * 32 + rowl) * EMBED + koff;
    const float* dp1 = dp0 + 16 * EMBED;
    const unsigned short* qhb = qh + rowl * EMBED + koff;
    const unsigned short* qlb = ql + rowl * EMBED + koff;

    // prologue: kb=0 doc regs
    float4 c00 = *(const float4*)dp0, c01 = *(const float4*)(dp0 + 4);
    float4 c10 = *(const float4*)dp1, c11 = *(const float4*)(dp1 + 4);

#define KBODY(kk, PREFETCH)                                                   \
    do {                                                                      \
        bf16x8 ah[4], al[4];                                                  \
        _Pragma("unroll")                                                     \
        for (int m = 0; m < 4; ++m) {                                         \
            ah[m] = *(const bf16x8*)(qhb + m * (16 * EMBED) + (kk));          \
            al[m] = *(const bf16x8*)(qlb + m * (16 * EMBED) + (kk));          \
        }                                                                     \
        float4 n00, n01, n10, n11;                                            \
        if (PREFETCH) {                                                       \
            n00 = *(const float4*)(dp0 + (kk) + 32);                          \
            n01 = *(const float4*)(dp0 + (kk) + 36);                          \
            n10 = *(const float4*)(dp1 + (kk) + 32);                          \
            n11 = *(const float4*)(dp1 + (kk) + 36);                          \
        }                                                                     \
        sq0 = dot8(c00, c01, sq0);                                            \
        sq1 = dot8(c10, c11, sq1);                                            \
        bf16x8 bh0, bl0, bh1, bl1;                                            \
        split8(c00, c01, bh0, bl0);                                           \
        split8(c10, c11, bh1, bl1);                                           \
        _Pragma("unroll")                                                     \
        for (int m = 0; m < 4; ++m)                                           \
            acc[0][m] = __builtin_amdgcn_mfma_f32_16x16x32_bf16(ah[m], bh0, acc[0][m], 0, 0, 0); \
        _Pragma("unroll")                                                     \
        for (int m = 0; m < 4; ++m)                                           \
            acc[1][m] = __builtin_amdgcn_mfma_f32_16x16x32_bf16(ah[m], bh1, acc[1][m], 0, 0, 0); \
        _Pragma("unroll")                                                     \
        for (int m = 0; m < 4; ++m)                                           \
            acc[0][m] = __builtin_amdgcn_mfma_f32_16x16x32_bf16(al[m], bh0, acc[0][m], 0, 0, 0); \
        _Pragma("unroll")                                                     \
        for (int m = 0; m < 4; ++m)                                           \
            acc[1][m] = __builtin_amdgcn_mfma_f32_16x16x32_bf16(al[m], bh1, acc[1][m], 0, 0, 0); \
        _Pragma("unroll")                                                     \
        for (int m = 0; m < 4; ++m)                                           \
            acc[0][m] = __builtin_amdgcn_mfma_f32_16x16x32_bf16(ah[m], bl0, acc[0][m], 0, 0, 0); \
        _Pragma("unroll")                                                     \
        for (int m = 0; m < 4; ++m)                                           \
            acc[1][m] = __builtin_amdgcn_mfma_f32_16x16x32_bf16(ah[m], bl1, acc[1][m], 0, 0, 0); \
        if (PREFETCH) { c00 = n00; c01 = n01; c10 = n10; c11 = n11; }         \
    } while (0)

#pragma unroll 1
    for (int kb = 0; kb < 11; ++kb) {
        KBODY(kb * 32, 1);
    }
    KBODY(352, 0);   // epilogue, no prefetch
#undef KBODY

    // doc norms: 4 lanes (l, l^16, l^32, l^48) share one doc row
    {
        float t0 = sq0;
        t0 += __shfl_xor(t0, 16);
        t0 += __shfl_xor(t0, 32);
        float rn0 = 1.0f / (sqrtf(t0) + EPSN);
        float t1 = sq1;
        t1 += __shfl_xor(t1, 16);
        t1 += __shfl_xor(t1, 32);
        float rn1 = 1.0f / (sqrtf(t1) + EPSN);
        const int q0 = (l >> 4) * 4;   // C/D: row=(lane>>4)*4+reg, col=lane&15
#pragma unroll
        for (int m = 0; m < 4; ++m) {
            f32x4 a = acc[0][m];
            const int col0 = w * 32 + rowl;
            S[(m * 16 + q0 + 0) * SC_STRIDE + col0] = a[0] * rn0;
            S[(m * 16 + q0 + 1) * SC_STRIDE + col0] = a[1] * rn0;
            S[(m * 16 + q0 + 2) * SC_STRIDE + col0] = a[2] * rn0;
            S[(m * 16 + q0 + 3) * SC_STRIDE + col0] = a[3] * rn0;
            f32x4 b = acc[1][m];
            const int col1 = w * 32 + 16 + rowl;
            S[(m * 16 + q0 + 0) * SC_STRIDE + col1] = b[0] * rn1;
            S[(m * 16 + q0 + 1) * SC_STRIDE + col1] = b[1] * rn1;
            S[(m * 16 + q0 + 2) * SC_STRIDE + col1] = b[2] * rn1;
            S[(m * 16 + q0 + 3) * SC_STRIDE + col1] = b[3] * rn1;
        }
    }
    __syncthreads();

    // 2-wave top-8 scan: thread t<128 scans a 64-doc half for query t&63
    float ts[8]; int ti[8];
#pragma unroll
    for (int r = 0; r < 8; ++r) { ts[r] = -3.402823466e38f; ti[r] = 0x7fffffff; }
    const int sq_ = tid & 63, half = tid >> 6;
    if (tid < 128) {
        for (int ii = 0; ii < 64; ++ii) {
            int d = half * 64 + ((ii + sq_) & 63);
            float sc = S[sq_ * SC_STRIDE + d];
            INS8(sc, d0 + d);
        }
    }
    __syncthreads();   // all scan reads of S complete
    if (half == 1 && tid < 128) {      // wave 1 parks its lists in (reused) S
#pragma unroll
        for (int r = 0; r < 8; ++r) {
            S[sq_ * 8 + r] = ts[r];
            S[512 + sq_ * 8 + r] = __int_as_float(ti[r]);
        }
    }
    __syncthreads();
    if (tid < 64) {                    // wave 0 merges + writes partials
#pragma unroll
        for (int r = 0; r < 8; ++r) {
            float s2 = S[sq_ * 8 + r];
            int i2 = __float_as_int(S[512 + sq_ * 8 + r]);
            INS8(s2, i2);
        }
        size_t o = ((size_t)sq_ * NBLK + blockIdx.x) * TOPK;
        *(float4*)&pscore[o]     = make_float4(ts[0], ts[1], ts[2], ts[3]);
        *(float4*)&pscore[o + 4] = make_float4(ts[4], ts[5], ts[6], ts[7]);
        *(int4*)&pidx[o]     = make_int4(ti[0], ti[1], ti[2], ti[3]);
        *(int4*)&pidx[o + 4] = make_int4(ti[4], ti[5], ti[6], ti[7]);
    }
}

__global__ __launch_bounds__(256) void merge_fuse_kernel(
        const float* __restrict__ docs, const float* __restrict__ pscore,
        const int* __restrict__ pidx, float* __restrict__ out) {
    const int q = blockIdx.x;
    const int tid = threadIdx.x;
    __shared__ float ls[2048];
    __shared__ int   li[2048];
    __shared__ float ls2[512];
    __shared__ int   li2[512];
    __shared__ float ls3[64];
    __shared__ int   li3[64];
    __shared__ int   fi[TOPK];
    __shared__ float wr[TOPK];

    const float* sp = pscore + (size_t)q * (NBLK * TOPK);
    const int*   ip = pidx   + (size_t)q * (NBLK * TOPK);

    float ts[8]; int ti[8];
#pragma unroll
    for (int r = 0; r < 8; ++r) { ts[r] = -3.402823466e38f; ti[r] = 0x7fffffff; }

    // level 0: coalesced float4 stream of 16384 candidates; idx loaded lazily
    for (int i = 0; i < 16; ++i) {
        int c4 = tid + (i << 8);
        float4 s = ((const float4*)sp)[c4];
        if (s.x >= ts[7] || s.y >= ts[7] || s.z >= ts[7] || s.w >= ts[7]) {
            int4 iv = ((const int4*)ip)[c4];
            INS8(s.x, iv.x); INS8(s.y, iv.y); INS8(s.z, iv.z); INS8(s.w, iv.w);
        }
    }
#pragma unroll
    for (int r = 0; r < 8; ++r) { ls[tid * 8 + r] = ts[r]; li[tid * 8 + r] = ti[r]; }
    __syncthreads();

    // level 1: 64 threads reduce 2048 -> 512 (interleaved, bank-clean)
    if (tid < 64) {
#pragma unroll
        for (int r = 0; r < 8; ++r) { ts[r] = -3.402823466e38f; ti[r] = 0x7fffffff; }
        for (int c = 0; c < 32; ++c) {
            int e = tid + c * 64;
            float s = ls[e]; int gi = li[e];
            INS8(s, gi);
        }
#pragma unroll
        for (int r = 0; r < 8; ++r) { ls2[tid * 8 + r] = ts[r]; li2[tid * 8 + r] = ti[r]; }
    }
    __syncthreads();

    // level 2: 8 threads reduce 512 -> 64
    if (tid < 8) {
#pragma unroll
        for (int r = 0; r < 8; ++r) { ts[r] = -3.402823466e38f; ti[r] = 0x7fffffff; }
        for (int c = 0; c < 64; ++c) {
            int e = tid + c * 8;
            float s = ls2[e]; int gi = li2[e];
            INS8(s, gi);
        }
#pragma unroll
        for (int r = 0; r < 8; ++r) { ls3[tid * 8 + r] = ts[r]; li3[tid * 8 + r] = ti[r]; }
    }
    __syncthreads();

    // level 3: thread 0 reduces 64 -> final 8; softmax; emit scores+idx
    if (tid == 0) {
#pragma unroll
        for (int r = 0; r < 8; ++r) { ts[r] = -3.402823466e38f; ti[r] = 0x7fffffff; }
        for (int e = 0; e < 64; ++e) {
            float s = ls3[e]; int gi = li3[e];
            INS8(s, gi);
        }
        float m = ts[0];  // sorted desc
        float w[8]; float sum = 0.f;
#pragma unroll
        for (int r = 0; r < 8; ++r) { w[r] = expf(ts[r] - m); sum += w[r]; }
        float rs = 1.0f / sum;
#pragma unroll
        for (int r = 0; r < 8; ++r) {
            fi[r] = ti[r];
            wr[r] = w[r] * rs;
            out[BATCH * EMBED + q * TOPK + r] = ts[r];
            out[BATCH * EMBED + BATCH * TOPK + q * TOPK + r] = (float)ti[r];
        }
    }
    __syncthreads();

    // fold retrieved-doc norm into weight: wr[r] /= (||d||+eps)
    int lane = tid & 63, wave = tid >> 6;
    for (int r = wave; r < TOPK; r += 4) {
        const float* dp = docs + (size_t)fi[r] * EMBED;
        float s = 0.f;
#pragma unroll
        for (int i = 0; i < 6; ++i) { float v = dp[lane + 64 * i]; s = fmaf(v, v, s); }
#pragma unroll
        for (int off = 32; off > 0; off >>= 1) s += __shfl_xor(s, off);
        if (lane == 0) wr[r] = wr[r] / (sqrtf(s) + EPSN);
    }
    __syncthreads();

    // fused[q][dim] = sum_r wr[r] * docs[fi[r]][dim]
    for (int dim = tid; dim < EMBED; dim += 256) {
        float a = 0.f;
#pragma unroll
        for (int r = 0; r < 8; ++r)
            a += wr[r] * docs[(size_t)fi[r] * EMBED + dim];
        out[q * EMBED + dim] = a;
    }
}

extern "C" void kernel_launch(void* const* d_in, const int* in_sizes, int n_in,
                              void* d_out, int out_size, void* d_ws, size_t ws_size,
                              hipStream_t stream) {
    const float* query = (const float*)d_in[0];
    const float* docs  = (const float*)d_in[1];
    float* out = (float*)d_out;

    char* ws = (char*)d_ws;
    unsigned short* qh = (unsigned short*)ws;                       // 48 KiB
    unsigned short* ql = (unsigned short*)(ws + 49152);             // 48 KiB
    float* pscore = (float*)(ws + 98304);                           // 4 MiB
    int*   pidx   = (int*)(ws + 98304 + (size_t)NBLK * BATCH * TOPK * 4);

    qprep_kernel<<<64, 64, 0, stream>>>(query, qh, ql);
    score_topk_kernel<<<NBLK, 256, 0, stream>>>(docs, qh, ql, pscore, pidx);
    merge_fuse_kernel<<<BATCH, 256, 0, stream>>>(docs, pscore, pidx, out);
}

// Round 4
// 277.704 us; speedup vs baseline: 1.4914x; 1.0375x over previous
//
#include <hip/hip_runtime.h>
#include <math.h>

// NanoRAG: cosine-sim retrieval + top-8 + softmax fusion.
// K0: normalize queries, split into bf16 hi/lo -> ws.qh/ws.ql
// K1: split-bf16 MFMA GEMM. Docs: global_load_lds -> wave-private swizzled
//     LDS tile, double-buffered, counted vmcnt (no barriers in K-loop).
//     Q: asm global_load_dwordx4 (L2-hot). Inline doc-norm. Per-block top-8.
// K2a: partial merge 2048 lists -> 8 chunk lists per q (512 blocks)
// K2b: final merge 64 -> top-8, softmax, gather+fuse -> d_out
//
// d_out layout (fp32): fused[64*384], scores[64*8], idx[64*8]

#define EMBED 384
#define NDOCS 262144
#define BATCH 64
#define TOPK 8
#define DBLK 128
#define NBLK (NDOCS / DBLK)   // 2048
#define EPSN 1e-8f
#define SC_STRIDE 132

typedef __attribute__((ext_vector_type(8))) short bf16x8;
typedef __attribute__((ext_vector_type(4))) float f32x4;

// register-resident sorted top-8 insertion (all indices compile-time)
#define INS8(s_, i_) do {                                                     \
    if ((s_) > ts[7] || ((s_) == ts[7] && (i_) < ti[7])) {                    \
        ts[7] = (s_); ti[7] = (i_);                                           \
        _Pragma("unroll")                                                     \
        for (int r_ = 7; r_ > 0; --r_) {                                      \
            bool sw_ = (ts[r_] > ts[r_-1]) ||                                 \
                       (ts[r_] == ts[r_-1] && ti[r_] < ti[r_-1]);             \
            float a_ = ts[r_-1]; int b_ = ti[r_-1];                           \
            ts[r_-1] = sw_ ? ts[r_] : a_;  ti[r_-1] = sw_ ? ti[r_] : b_;      \
            ts[r_]   = sw_ ? a_ : ts[r_];  ti[r_]   = sw_ ? b_ : ti[r_];      \
        }                                                                     \
    }                                                                         \
} while (0)

// RNE split of fp32 (as f32x4 pair) into bf16 high + low parts
__device__ __forceinline__ void split8v(f32x4 f0, f32x4 f1, bf16x8& bh, bf16x8& bl) {
    float f[8] = {f0[0], f0[1], f0[2], f0[3], f1[0], f1[1], f1[2], f1[3]};
#pragma unroll
    for (int i = 0; i < 8; ++i) {
        unsigned u = __float_as_uint(f[i]);
        unsigned h = (u + 0x7fffu + ((u >> 16) & 1u)) >> 16;
        float fh = __uint_as_float(h << 16);
        float r = f[i] - fh;                      // exact
        unsigned v = __float_as_uint(r);
        unsigned lo = (v + 0x7fffu + ((v >> 16) & 1u)) >> 16;
        bh[i] = (short)h;
        bl[i] = (short)lo;
    }
}

__device__ __forceinline__ float dot8v(f32x4 f0, f32x4 f1, float s) {
#pragma unroll
    for (int i = 0; i < 4; ++i) s = fmaf(f0[i], f0[i], s);
#pragma unroll
    for (int i = 0; i < 4; ++i) s = fmaf(f1[i], f1[i], s);
    return s;
}

__device__ __forceinline__ int4 gload16(const void* p) {
    int4 r;
    asm volatile("global_load_dwordx4 %0, %1, off" : "=v"(r) : "v"(p) : "memory");
    return r;
}

__device__ __forceinline__ f32x4 dsread16(unsigned a) {
    f32x4 r;
    asm volatile("ds_read_b128 %0, %1" : "=v"(r) : "v"(a) : "memory");
    return r;
}

__global__ void qprep_kernel(const float* __restrict__ q,
                             unsigned short* __restrict__ qh,
                             unsigned short* __restrict__ ql) {
    const int row = blockIdx.x;     // 64 blocks
    const int lane = threadIdx.x;   // 64 threads
    float v[6];
    float s = 0.f;
#pragma unroll
    for (int i = 0; i < 6; ++i) {
        v[i] = q[row * EMBED + lane + 64 * i];
        s = fmaf(v[i], v[i], s);
    }
#pragma unroll
    for (int off = 32; off > 0; off >>= 1) s += __shfl_xor(s, off);
    float rinv = 1.0f / (sqrtf(s) + EPSN);
#pragma unroll
    for (int i = 0; i < 6; ++i) {
        float f = v[i] * rinv;
        unsigned u = __float_as_uint(f);
        unsigned h = (u + 0x7fffu + ((u >> 16) & 1u)) >> 16;
        float fh = __uint_as_float(h << 16);
        float r = f - fh;
        unsigned vv = __float_as_uint(r);
        unsigned lo = (vv + 0x7fffu + ((vv >> 16) & 1u)) >> 16;
        qh[row * EMBED + lane + 64 * i] = (unsigned short)h;
        ql[row * EMBED + lane + 64 * i] = (unsigned short)lo;
    }
}

__global__ __launch_bounds__(256, 4) void score_topk_kernel(
        const float* __restrict__ docs,
        const unsigned short* __restrict__ qh,
        const unsigned short* __restrict__ ql,
        float* __restrict__ pscore, int* __restrict__ pidx) {
    // LDS: doc staging buf0 @0 (16KB), buf1 @16384 (16KB), each wave-private
    // 32 rows x 32 floats, XOR-swizzled. Epilogue overlays S[64][132] @0.
    __shared__ __align__(16) char smem[34816];

    const int tid = threadIdx.x;
    const int l = tid & 63;
    const int wv = tid >> 6;           // wave 0..3 -> 32-doc group
    const int rowl = l & 15;           // B col within fragment
    const int ksub = l >> 4;           // k sub-block (x8 elems)
    const int d0 = blockIdx.x * DBLK;

    f32x4 acc[2][4];
#pragma unroll
    for (int s = 0; s < 2; ++s)
#pragma unroll
        for (int m = 0; m < 4; ++m) acc[s][m] = (f32x4){0.f, 0.f, 0.f, 0.f};
    float sq0 = 0.f, sq1 = 0.f;

    // stage source: lane l loads 16B of row wv*32 + j*8 + (l>>3), with the
    // XOR-swizzle ((l&7)^(l>>3))<<4 pre-applied to the byte-in-row (rule #21)
    const float* sgsrc = docs + (size_t)(d0 + wv * 32 + (l >> 3)) * EMBED
                              + (((l & 7) ^ (l >> 3)) << 2);
    const unsigned short* qhb = qh + rowl * EMBED + ksub * 8;
    const unsigned short* qlb = ql + rowl * EMBED + ksub * 8;

    const unsigned bufb = (unsigned)(uintptr_t)smem;
    // ds_read offsets: row (s*16+rowl) stride 128B, swizzled k-bytes
    const unsigned off00 = wv * 4096 + rowl * 128 + ((ksub * 32 +  0) ^ ((rowl & 7) << 4));
    const unsigned off01 = wv * 4096 + rowl * 128 + ((ksub * 32 + 16) ^ ((rowl & 7) << 4));
    const unsigned off10 = off00 + 2048;
    const unsigned off11 = off01 + 2048;

    // prologue: stage tile kb=0 into buf0
    {
        float* db = (float*)smem + wv * 1024;
#pragma unroll
        for (int j = 0; j < 4; ++j)
            __builtin_amdgcn_global_load_lds(sgsrc + j * 3072, db + j * 256, 16, 0, 0);
    }

#define SCORE_ITER(KB, DO_STAGE, VM1, VM2)                                     \
    {                                                                          \
        int4 qr[8];                                                            \
        _Pragma("unroll")                                                      \
        for (int m = 0; m < 4; ++m) {                                          \
            qr[m]     = gload16(qhb + m * (16 * EMBED) + (KB) * 32);           \
            qr[4 + m] = gload16(qlb + m * (16 * EMBED) + (KB) * 32);           \
        }                                                                      \
        if (DO_STAGE) {                                                        \
            float* db = (float*)(smem + (((KB) + 1) & 1) * 16384) + wv * 1024; \
            _Pragma("unroll")                                                  \
            for (int j = 0; j < 4; ++j)                                        \
                __builtin_amdgcn_global_load_lds(                              \
                    sgsrc + j * 3072 + ((KB) + 1) * 32, db + j * 256, 16, 0, 0);\
        }                                                                      \
        asm volatile("s_waitcnt " VM1 ::: "memory");                           \
        unsigned pb = bufb + ((KB) & 1) * 16384;                               \
        f32x4 d00 = dsread16(pb + off00);                                      \
        f32x4 d01 = dsread16(pb + off01);                                      \
        f32x4 d10 = dsread16(pb + off10);                                      \
        f32x4 d11 = dsread16(pb + off11);                                      \
        asm volatile("s_waitcnt " VM2 " lgkmcnt(0)" ::: "memory");             \
        __builtin_amdgcn_sched_barrier(0);                                     \
        sq0 = dot8v(d00, d01, sq0);                                            \
        sq1 = dot8v(d10, d11, sq1);                                            \
        bf16x8 bh0, bl0, bh1, bl1;                                             \
        split8v(d00, d01, bh0, bl0);                                           \
        split8v(d10, d11, bh1, bl1);                                           \
        _Pragma("unroll")                                                      \
        for (int m = 0; m < 4; ++m) {                                          \
            bf16x8 ah = *(bf16x8*)&qr[m];                                      \
            bf16x8 al = *(bf16x8*)&qr[4 + m];                                  \
            acc[0][m] = __builtin_amdgcn_mfma_f32_16x16x32_bf16(ah, bh0, acc[0][m], 0, 0, 0); \
            acc[1][m] = __builtin_amdgcn_mfma_f32_16x16x32_bf16(ah, bh1, acc[1][m], 0, 0, 0); \
            acc[0][m] = __builtin_amdgcn_mfma_f32_16x16x32_bf16(al, bh0, acc[0][m], 0, 0, 0); \
            acc[1][m] = __builtin_amdgcn_mfma_f32_16x16x32_bf16(al, bh1, acc[1][m], 0, 0, 0); \
            acc[0][m] = __builtin_amdgcn_mfma_f32_16x16x32_bf16(ah, bl0, acc[0][m], 0, 0, 0); \
            acc[1][m] = __builtin_amdgcn_mfma_f32_16x16x32_bf16(ah, bl1, acc[1][m], 0, 0, 0); \
        }                                                                      \
    }

    // steady: FIFO [stage(kb) 4][q(kb) 8][stage(kb+1) 4]; vmcnt(12) drains
    // only stage(kb); vmcnt(4) drains q(kb), keeps stage(kb+1) in flight.
#pragma unroll 1
    for (int kb = 0; kb < 11; ++kb) {
        SCORE_ITER(kb, 1, "vmcnt(12)", "vmcnt(4)")
    }
    SCORE_ITER(11, 0, "vmcnt(8)", "vmcnt(0)")
#undef SCORE_ITER

    __syncthreads();   // staging regions dead; safe to overlay S

    float* S = (float*)smem;
    {
        float t0 = sq0;
        t0 += __shfl_xor(t0, 16);
        t0 += __shfl_xor(t0, 32);
        float rn0 = 1.0f / (sqrtf(t0) + EPSN);
        float t1 = sq1;
        t1 += __shfl_xor(t1, 16);
        t1 += __shfl_xor(t1, 32);
        float rn1 = 1.0f / (sqrtf(t1) + EPSN);
        const int q0 = ksub * 4;       // C/D: row=(lane>>4)*4+reg, col=lane&15
        const int col0 = wv * 32 + rowl;
        const int col1 = col0 + 16;
#pragma unroll
        for (int m = 0; m < 4; ++m) {
            f32x4 a = acc[0][m];
            S[(m * 16 + q0 + 0) * SC_STRIDE + col0] = a[0] * rn0;
            S[(m * 16 + q0 + 1) * SC_STRIDE + col0] = a[1] * rn0;
            S[(m * 16 + q0 + 2) * SC_STRIDE + col0] = a[2] * rn0;
            S[(m * 16 + q0 + 3) * SC_STRIDE + col0] = a[3] * rn0;
            f32x4 b = acc[1][m];
            S[(m * 16 + q0 + 0) * SC_STRIDE + col1] = b[0] * rn1;
            S[(m * 16 + q0 + 1) * SC_STRIDE + col1] = b[1] * rn1;
            S[(m * 16 + q0 + 2) * SC_STRIDE + col1] = b[2] * rn1;
            S[(m * 16 + q0 + 3) * SC_STRIDE + col1] = b[3] * rn1;
        }
    }
    __syncthreads();

    // 2-wave top-8 scan: thread t<128 scans a 64-doc half for query t&63
    float ts[8]; int ti[8];
#pragma unroll
    for (int r = 0; r < 8; ++r) { ts[r] = -3.402823466e38f; ti[r] = 0x7fffffff; }
    const int sq_ = tid & 63, half = tid >> 6;
    if (tid < 128) {
        for (int ii = 0; ii < 64; ++ii) {
            int d = half * 64 + ((ii + sq_) & 63);
            float sc = S[sq_ * SC_STRIDE + d];
            INS8(sc, d0 + d);
        }
    }
    __syncthreads();
    if (half == 1 && tid < 128) {
#pragma unroll
        for (int r = 0; r < 8; ++r) {
            S[sq_ * 8 + r] = ts[r];
            S[512 + sq_ * 8 + r] = __int_as_float(ti[r]);
        }
    }
    __syncthreads();
    if (tid < 64) {
#pragma unroll
        for (int r = 0; r < 8; ++r) {
            float s2 = S[sq_ * 8 + r];
            int i2 = __float_as_int(S[512 + sq_ * 8 + r]);
            INS8(s2, i2);
        }
        size_t o = ((size_t)sq_ * NBLK + blockIdx.x) * TOPK;
        *(float4*)&pscore[o]     = make_float4(ts[0], ts[1], ts[2], ts[3]);
        *(float4*)&pscore[o + 4] = make_float4(ts[4], ts[5], ts[6], ts[7]);
        *(int4*)&pidx[o]     = make_int4(ti[0], ti[1], ti[2], ti[3]);
        *(int4*)&pidx[o + 4] = make_int4(ti[4], ti[5], ti[6], ti[7]);
    }
}

// stage A: block (q, c) merges lists c*256..c*256+255 -> one top-8 chunk list
__global__ __launch_bounds__(256) void merge_a_kernel(
        const float* __restrict__ pscore, const int* __restrict__ pidx,
        float* __restrict__ cs, int* __restrict__ ci) {
    const int q = blockIdx.x >> 3;
    const int c = blockIdx.x & 7;
    const int tid = threadIdx.x;
    __shared__ float ls[2048];
    __shared__ int   li[2048];
    __shared__ float ls2[512];
    __shared__ int   li2[512];
    __shared__ float ls3[64];
    __shared__ int   li3[64];

    // L0: one sorted list per thread -> its top8 IS the list
    {
        size_t o = ((size_t)q * NBLK + c * 256 + tid) * TOPK;
        float4 s0 = *(const float4*)&pscore[o];
        float4 s1 = *(const float4*)&pscore[o + 4];
        int4 i0 = *(const int4*)&pidx[o];
        int4 i1 = *(const int4*)&pidx[o + 4];
        ls[tid * 8 + 0] = s0.x; ls[tid * 8 + 1] = s0.y;
        ls[tid * 8 + 2] = s0.z; ls[tid * 8 + 3] = s0.w;
        ls[tid * 8 + 4] = s1.x; ls[tid * 8 + 5] = s1.y;
        ls[tid * 8 + 6] = s1.z; ls[tid * 8 + 7] = s1.w;
        li[tid * 8 + 0] = i0.x; li[tid * 8 + 1] = i0.y;
        li[tid * 8 + 2] = i0.z; li[tid * 8 + 3] = i0.w;
        li[tid * 8 + 4] = i1.x; li[tid * 8 + 5] = i1.y;
        li[tid * 8 + 6] = i1.z; li[tid * 8 + 7] = i1.w;
    }
    __syncthreads();

    float ts[8]; int ti[8];
    // L1: 64 threads x 32 entries -> 512
    if (tid < 64) {
#pragma unroll
        for (int r = 0; r < 8; ++r) { ts[r] = -3.402823466e38f; ti[r] = 0x7fffffff; }
        for (int e = 0; e < 32; ++e) {
            int k = tid + e * 64;
            float s = ls[k]; int gi = li[k];
            INS8(s, gi);
        }
#pragma unroll
        for (int r = 0; r < 8; ++r) { ls2[tid * 8 + r] = ts[r]; li2[tid * 8 + r] = ti[r]; }
    }
    __syncthreads();
    // L2: 8 threads x 64 -> 64
    if (tid < 8) {
#pragma unroll
        for (int r = 0; r < 8; ++r) { ts[r] = -3.402823466e38f; ti[r] = 0x7fffffff; }
        for (int e = 0; e < 64; ++e) {
            int k = tid + e * 8;
            float s = ls2[k]; int gi = li2[k];
            INS8(s, gi);
        }
#pragma unroll
        for (int r = 0; r < 8; ++r) { ls3[tid * 8 + r] = ts[r]; li3[tid * 8 + r] = ti[r]; }
    }
    __syncthreads();
    // L3: thread 0 x 64 -> chunk top-8
    if (tid == 0) {
#pragma unroll
        for (int r = 0; r < 8; ++r) { ts[r] = -3.402823466e38f; ti[r] = 0x7fffffff; }
        for (int e = 0; e < 64; ++e) {
            float s = ls3[e]; int gi = li3[e];
            INS8(s, gi);
        }
        size_t o = (size_t)(q * 8 + c) * TOPK;
#pragma unroll
        for (int r = 0; r < 8; ++r) { cs[o + r] = ts[r]; ci[o + r] = ti[r]; }
    }
}

// stage B: final merge (64 candidates), softmax, gather+fuse
__global__ __launch_bounds__(256) void merge_b_kernel(
        const float* __restrict__ docs, const float* __restrict__ cs,
        const int* __restrict__ ci, float* __restrict__ out) {
    const int q = blockIdx.x;
    const int tid = threadIdx.x;
    __shared__ int   fi[TOPK];
    __shared__ float wr[TOPK];

    if (tid == 0) {
        float ts[8]; int ti[8];
#pragma unroll
        for (int r = 0; r < 8; ++r) { ts[r] = -3.402823466e38f; ti[r] = 0x7fffffff; }
        for (int e = 0; e < 64; ++e) {
            float s = cs[q * 64 + e]; int gi = ci[q * 64 + e];
            INS8(s, gi);
        }
        float m = ts[0];
        float w[8]; float sum = 0.f;
#pragma unroll
        for (int r = 0; r < 8; ++r) { w[r] = expf(ts[r] - m); sum += w[r]; }
        float rs = 1.0f / sum;
#pragma unroll
        for (int r = 0; r < 8; ++r) {
            fi[r] = ti[r];
            wr[r] = w[r] * rs;
            out[BATCH * EMBED + q * TOPK + r] = ts[r];
            out[BATCH * EMBED + BATCH * TOPK + q * TOPK + r] = (float)ti[r];
        }
    }
    __syncthreads();

    // fold retrieved-doc norm into weight: wr[r] /= (||d||+eps)
    int lane = tid & 63, wave = tid >> 6;
    for (int r = wave; r < TOPK; r += 4) {
        const float* dp = docs + (size_t)fi[r] * EMBED;
        float s = 0.f;
#pragma unroll
        for (int i = 0; i < 6; ++i) { float v = dp[lane + 64 * i]; s = fmaf(v, v, s); }
#pragma unroll
        for (int off = 32; off > 0; off >>= 1) s += __shfl_xor(s, off);
        if (lane == 0) wr[r] = wr[r] / (sqrtf(s) + EPSN);
    }
    __syncthreads();

    for (int dim = tid; dim < EMBED; dim += 256) {
        float a = 0.f;
#pragma unroll
        for (int r = 0; r < 8; ++r)
            a += wr[r] * docs[(size_t)fi[r] * EMBED + dim];
        out[q * EMBED + dim] = a;
    }
}

extern "C" void kernel_launch(void* const* d_in, const int* in_sizes, int n_in,
                              void* d_out, int out_size, void* d_ws, size_t ws_size,
                              hipStream_t stream) {
    const float* query = (const float*)d_in[0];
    const float* docs  = (const float*)d_in[1];
    float* out = (float*)d_out;

    char* ws = (char*)d_ws;
    unsigned short* qh = (unsigned short*)ws;                       // 48 KiB
    unsigned short* ql = (unsigned short*)(ws + 49152);             // 48 KiB
    float* pscore = (float*)(ws + 98304);                           // 4 MiB
    int*   pidx   = (int*)(ws + 98304 + (size_t)NBLK * BATCH * TOPK * 4);
    char*  ws3    = ws + 98304 + 2 * (size_t)NBLK * BATCH * TOPK * 4;
    float* cs     = (float*)ws3;                                    // 16 KiB
    int*   ci     = (int*)(ws3 + BATCH * 8 * TOPK * 4);

    qprep_kernel<<<64, 64, 0, stream>>>(query, qh, ql);
    score_topk_kernel<<<NBLK, 256, 0, stream>>>(docs, qh, ql, pscore, pidx);
    merge_a_kernel<<<BATCH * 8, 256, 0, stream>>>(pscore, pidx, cs, ci);
    merge_b_kernel<<<BATCH, 256, 0, stream>>>(docs, cs, ci, out);
}

// Round 6
// 238.897 us; speedup vs baseline: 1.7336x; 1.1624x over previous
//
#include <hip/hip_runtime.h>
#include <math.h>

// NanoRAG: cosine-sim retrieval + top-8 + softmax fusion.
// K0: normalize queries, split into bf16 hi/lo -> ws.qh/ws.ql
// K1: split-bf16 MFMA GEMM, 256 docs/block, docs+q double-buffered in
//     REGISTERS (asm loads), ONE counted vmcnt(16) wait per k-iter, no
//     barriers/LDS in K-loop. Manual RNE split (proven numerics).
//     Inline doc-norm. Per-block top-8.
// K2a: partial merge 1024 lists -> 4 chunk lists per q (256 blocks)
// K2b: final merge 32 -> top-8, softmax, gather+fuse -> d_out
//
// d_out layout (fp32): fused[64*384], scores[64*8], idx[64*8]

#define EMBED 384
#define NDOCS 262144
#define BATCH 64
#define TOPK 8
#define DBLK 256
#define NBLK (NDOCS / DBLK)   // 1024
#define EPSN 1e-8f
#define SCW 260               // score tile stride (words)

typedef __attribute__((ext_vector_type(8))) short bf16x8;
typedef __attribute__((ext_vector_type(4))) float f32x4;

// register-resident sorted top-8 insertion (all indices compile-time)
#define INS8(s_, i_) do {                                                     \
    if ((s_) > ts[7] || ((s_) == ts[7] && (i_) < ti[7])) {                    \
        ts[7] = (s_); ti[7] = (i_);                                           \
        _Pragma("unroll")                                                     \
        for (int r_ = 7; r_ > 0; --r_) {                                      \
            bool sw_ = (ts[r_] > ts[r_-1]) ||                                 \
                       (ts[r_] == ts[r_-1] && ti[r_] < ti[r_-1]);             \
            float a_ = ts[r_-1]; int b_ = ti[r_-1];                           \
            ts[r_-1] = sw_ ? ts[r_] : a_;  ti[r_-1] = sw_ ? ti[r_] : b_;      \
            ts[r_]   = sw_ ? a_ : ts[r_];  ti[r_]   = sw_ ? b_ : ti[r_];      \
        }                                                                     \
    }                                                                         \
} while (0)

template<int OFF>
__device__ __forceinline__ int4 gload16o(const void* p) {
    int4 r;
    asm volatile("global_load_dwordx4 %0, %1, off offset:%2"
                 : "=v"(r) : "v"(p), "i"(OFF) : "memory");
    return r;
}

// Manual RNE split of fp32 into bf16 hi + lo: f ~= hi + lo, |err| <= 2^-18|f|.
// PROVEN numerics (rounds 2-4 passed at absmax 3e-5) — do NOT substitute
// v_cvt_pk_bf16_f32 here: its rounding flipped a near-tie top-k index (R4).
__device__ __forceinline__ void split8v(f32x4 f0, f32x4 f1, bf16x8& bh, bf16x8& bl) {
    float f[8] = {f0[0], f0[1], f0[2], f0[3], f1[0], f1[1], f1[2], f1[3]};
#pragma unroll
    for (int i = 0; i < 8; ++i) {
        unsigned u = __float_as_uint(f[i]);
        unsigned h = (u + 0x7fffu + ((u >> 16) & 1u)) >> 16;
        float fh = __uint_as_float(h << 16);
        float r = f[i] - fh;                      // exact
        unsigned v = __float_as_uint(r);
        unsigned lo = (v + 0x7fffu + ((v >> 16) & 1u)) >> 16;
        bh[i] = (short)h;
        bl[i] = (short)lo;
    }
}

__device__ __forceinline__ float dot8v(f32x4 f0, f32x4 f1, float s) {
#pragma unroll
    for (int i = 0; i < 4; ++i) s = fmaf(f0[i], f0[i], s);
#pragma unroll
    for (int i = 0; i < 4; ++i) s = fmaf(f1[i], f1[i], s);
    return s;
}

__global__ void qprep_kernel(const float* __restrict__ q,
                             unsigned short* __restrict__ qh,
                             unsigned short* __restrict__ ql) {
    const int row = blockIdx.x;     // 64 blocks
    const int lane = threadIdx.x;   // 64 threads
    float v[6];
    float s = 0.f;
#pragma unroll
    for (int i = 0; i < 6; ++i) {
        v[i] = q[row * EMBED + lane + 64 * i];
        s = fmaf(v[i], v[i], s);
    }
#pragma unroll
    for (int off = 32; off > 0; off >>= 1) s += __shfl_xor(s, off);
    float rinv = 1.0f / (sqrtf(s) + EPSN);
#pragma unroll
    for (int i = 0; i < 6; ++i) {
        float f = v[i] * rinv;
        unsigned u = __float_as_uint(f);
        unsigned h = (u + 0x7fffu + ((u >> 16) & 1u)) >> 16;
        float fh = __uint_as_float(h << 16);
        float r = f - fh;
        unsigned vv = __float_as_uint(r);
        unsigned lo = (vv + 0x7fffu + ((vv >> 16) & 1u)) >> 16;
        qh[row * EMBED + lane + 64 * i] = (unsigned short)h;
        ql[row * EMBED + lane + 64 * i] = (unsigned short)lo;
    }
}

__global__ __launch_bounds__(256, 2) void score_topk_kernel(
        const float* __restrict__ docs,
        const unsigned short* __restrict__ qh,
        const unsigned short* __restrict__ ql,
        float* __restrict__ pscore, int* __restrict__ pidx) {
    __shared__ float S[BATCH * SCW];   // 64 x 260 score tile, 66.6 KB

    const int tid = threadIdx.x;
    const int l = tid & 63;
    const int wv = tid >> 6;           // wave -> 64-doc group
    const int rowl = l & 15;
    const int ksub = l >> 4;
    const int d0 = blockIdx.x * DBLK;

    f32x4 acc[4][4];                   // [strip][mtile]
#pragma unroll
    for (int s = 0; s < 4; ++s)
#pragma unroll
        for (int m = 0; m < 4; ++m) acc[s][m] = (f32x4){0.f, 0.f, 0.f, 0.f};
    float sq[4] = {0.f, 0.f, 0.f, 0.f};

    const float* dbase[4];
#pragma unroll
    for (int s = 0; s < 4; ++s)
        dbase[s] = docs + (size_t)(d0 + wv * 64 + s * 16 + rowl) * EMBED + ksub * 8;
    const unsigned short* qb_[8];
#pragma unroll
    for (int m = 0; m < 4; ++m) {
        qb_[m]     = qh + (m * 16 + rowl) * EMBED + ksub * 8;
        qb_[4 + m] = ql + (m * 16 + rowl) * EMBED + ksub * 8;
    }

    int4 qA[8], qB[8], dA[8], dB[8];

    // prologue: kb=0 into set A (16 outstanding)
#pragma unroll
    for (int m = 0; m < 8; ++m) qA[m] = gload16o<0>(qb_[m]);
#pragma unroll
    for (int s = 0; s < 4; ++s) {
        dA[2 * s]     = gload16o<0>(dbase[s]);
        dA[2 * s + 1] = gload16o<16>(dbase[s]);
    }

#define ITER(KB, QC, DC, QN, DN, PF, VM)                                       \
    {                                                                          \
        if (PF) {                                                              \
            _Pragma("unroll")                                                  \
            for (int m = 0; m < 8; ++m)                                        \
                QN[m] = gload16o<((KB) + 1) * 64>(qb_[m]);                     \
            _Pragma("unroll")                                                  \
            for (int s = 0; s < 4; ++s) {                                      \
                DN[2 * s]     = gload16o<((KB) + 1) * 128>(dbase[s]);          \
                DN[2 * s + 1] = gload16o<((KB) + 1) * 128 + 16>(dbase[s]);     \
            }                                                                  \
        }                                                                      \
        asm volatile("s_waitcnt " VM ::: "memory");                            \
        __builtin_amdgcn_sched_barrier(0);                                     \
        _Pragma("unroll")                                                      \
        for (int s = 0; s < 4; ++s) {                                          \
            f32x4 fa = *(f32x4*)&DC[2 * s];                                    \
            f32x4 fb = *(f32x4*)&DC[2 * s + 1];                                \
            sq[s] = dot8v(fa, fb, sq[s]);                                      \
            bf16x8 bh, bl;                                                     \
            split8v(fa, fb, bh, bl);                                           \
            _Pragma("unroll")                                                  \
            for (int m = 0; m < 4; ++m) {                                      \
                bf16x8 ah = *(bf16x8*)&QC[m];                                  \
                bf16x8 al = *(bf16x8*)&QC[4 + m];                              \
                acc[s][m] = __builtin_amdgcn_mfma_f32_16x16x32_bf16(ah, bh, acc[s][m], 0, 0, 0); \
                acc[s][m] = __builtin_amdgcn_mfma_f32_16x16x32_bf16(al, bh, acc[s][m], 0, 0, 0); \
                acc[s][m] = __builtin_amdgcn_mfma_f32_16x16x32_bf16(ah, bl, acc[s][m], 0, 0, 0); \
            }                                                                  \
        }                                                                      \
    }

    ITER(0,  qA, dA, qB, dB, 1, "vmcnt(16)")
    ITER(1,  qB, dB, qA, dA, 1, "vmcnt(16)")
    ITER(2,  qA, dA, qB, dB, 1, "vmcnt(16)")
    ITER(3,  qB, dB, qA, dA, 1, "vmcnt(16)")
    ITER(4,  qA, dA, qB, dB, 1, "vmcnt(16)")
    ITER(5,  qB, dB, qA, dA, 1, "vmcnt(16)")
    ITER(6,  qA, dA, qB, dB, 1, "vmcnt(16)")
    ITER(7,  qB, dB, qA, dA, 1, "vmcnt(16)")
    ITER(8,  qA, dA, qB, dB, 1, "vmcnt(16)")
    ITER(9,  qB, dB, qA, dA, 1, "vmcnt(16)")
    ITER(10, qA, dA, qB, dB, 1, "vmcnt(16)")
    ITER(11, qB, dB, qA, dA, 0, "vmcnt(0)")
#undef ITER

    // doc norms (lanes l, l^16, l^32, l^48 share a doc row) + score tile
#pragma unroll
    for (int s = 0; s < 4; ++s) {
        float t = sq[s];
        t += __shfl_xor(t, 16);
        t += __shfl_xor(t, 32);
        float rn = 1.0f / (sqrtf(t) + EPSN);
        const int col = wv * 64 + s * 16 + rowl;
        const int q0 = ksub * 4;       // C/D: row=(lane>>4)*4+reg, col=lane&15
#pragma unroll
        for (int m = 0; m < 4; ++m) {
            f32x4 a = acc[s][m];
#pragma unroll
            for (int j = 0; j < 4; ++j)
                S[(m * 16 + q0 + j) * SCW + col] = a[j] * rn;
        }
    }
    __syncthreads();

    // top-8: thread t scans query t&63 over quarter (t>>6)*64..+63, staggered
    float ts[8]; int ti[8];
#pragma unroll
    for (int r = 0; r < 8; ++r) { ts[r] = -3.402823466e38f; ti[r] = 0x7fffffff; }
    const int q = tid & 63, qa = tid >> 6;
    for (int ii = 0; ii < 64; ++ii) {
        int d = qa * 64 + ((ii + q) & 63);
        float sc = S[q * SCW + d];
        INS8(sc, d0 + d);
    }
    __syncthreads();   // all S reads done; safe to overwrite
#pragma unroll
    for (int r = 0; r < 8; ++r) {
        S[(qa * 64 + q) * 8 + r] = ts[r];
        S[2048 + (qa * 64 + q) * 8 + r] = __int_as_float(ti[r]);
    }
    __syncthreads();
    if (tid < 64) {
#pragma unroll
        for (int r = 0; r < 8; ++r) { ts[r] = -3.402823466e38f; ti[r] = 0x7fffffff; }
        for (int a = 0; a < 4; ++a) {
#pragma unroll
            for (int r = 0; r < 8; ++r) {
                float s2 = S[(a * 64 + q) * 8 + r];
                int i2 = __float_as_int(S[2048 + (a * 64 + q) * 8 + r]);
                INS8(s2, i2);
            }
        }
        size_t o = ((size_t)q * NBLK + blockIdx.x) * TOPK;
        *(float4*)&pscore[o]     = make_float4(ts[0], ts[1], ts[2], ts[3]);
        *(float4*)&pscore[o + 4] = make_float4(ts[4], ts[5], ts[6], ts[7]);
        *(int4*)&pidx[o]     = make_int4(ti[0], ti[1], ti[2], ti[3]);
        *(int4*)&pidx[o + 4] = make_int4(ti[4], ti[5], ti[6], ti[7]);
    }
}

// stage A: block (q, c) merges lists c*256..c*256+255 -> one top-8 chunk list
__global__ __launch_bounds__(256) void merge_a_kernel(
        const float* __restrict__ pscore, const int* __restrict__ pidx,
        float* __restrict__ cs, int* __restrict__ ci) {
    const int q = blockIdx.x >> 2;
    const int c = blockIdx.x & 3;
    const int tid = threadIdx.x;
    __shared__ float ls[2048];
    __shared__ int   li[2048];
    __shared__ float ls2[512];
    __shared__ int   li2[512];
    __shared__ float ls3[64];
    __shared__ int   li3[64];

    {
        size_t o = ((size_t)q * NBLK + c * 256 + tid) * TOPK;
        float4 s0 = *(const float4*)&pscore[o];
        float4 s1 = *(const float4*)&pscore[o + 4];
        int4 i0 = *(const int4*)&pidx[o];
        int4 i1 = *(const int4*)&pidx[o + 4];
        ls[tid * 8 + 0] = s0.x; ls[tid * 8 + 1] = s0.y;
        ls[tid * 8 + 2] = s0.z; ls[tid * 8 + 3] = s0.w;
        ls[tid * 8 + 4] = s1.x; ls[tid * 8 + 5] = s1.y;
        ls[tid * 8 + 6] = s1.z; ls[tid * 8 + 7] = s1.w;
        li[tid * 8 + 0] = i0.x; li[tid * 8 + 1] = i0.y;
        li[tid * 8 + 2] = i0.z; li[tid * 8 + 3] = i0.w;
        li[tid * 8 + 4] = i1.x; li[tid * 8 + 5] = i1.y;
        li[tid * 8 + 6] = i1.z; li[tid * 8 + 7] = i1.w;
    }
    __syncthreads();

    float ts[8]; int ti[8];
    if (tid < 64) {
#pragma unroll
        for (int r = 0; r < 8; ++r) { ts[r] = -3.402823466e38f; ti[r] = 0x7fffffff; }
        for (int e = 0; e < 32; ++e) {
            int k = tid + e * 64;
            float s = ls[k]; int gi = li[k];
            INS8(s, gi);
        }
#pragma unroll
        for (int r = 0; r < 8; ++r) { ls2[tid * 8 + r] = ts[r]; li2[tid * 8 + r] = ti[r]; }
    }
    __syncthreads();
    if (tid < 8) {
#pragma unroll
        for (int r = 0; r < 8; ++r) { ts[r] = -3.402823466e38f; ti[r] = 0x7fffffff; }
        for (int e = 0; e < 64; ++e) {
            int k = tid + e * 8;
            float s = ls2[k]; int gi = li2[k];
            INS8(s, gi);
        }
#pragma unroll
        for (int r = 0; r < 8; ++r) { ls3[tid * 8 + r] = ts[r]; li3[tid * 8 + r] = ti[r]; }
    }
    __syncthreads();
    if (tid == 0) {
#pragma unroll
        for (int r = 0; r < 8; ++r) { ts[r] = -3.402823466e38f; ti[r] = 0x7fffffff; }
        for (int e = 0; e < 64; ++e) {
            float s = ls3[e]; int gi = li3[e];
            INS8(s, gi);
        }
        size_t o = (size_t)(q * 4 + c) * TOPK;
#pragma unroll
        for (int r = 0; r < 8; ++r) { cs[o + r] = ts[r]; ci[o + r] = ti[r]; }
    }
}

// stage B: final merge (32 candidates), softmax, gather+fuse
__global__ __launch_bounds__(256) void merge_b_kernel(
        const float* __restrict__ docs, const float* __restrict__ cs,
        const int* __restrict__ ci, float* __restrict__ out) {
    const int q = blockIdx.x;
    const int tid = threadIdx.x;
    __shared__ int   fi[TOPK];
    __shared__ float wr[TOPK];

    if (tid == 0) {
        float ts[8]; int ti[8];
#pragma unroll
        for (int r = 0; r < 8; ++r) { ts[r] = -3.402823466e38f; ti[r] = 0x7fffffff; }
        for (int e = 0; e < 32; ++e) {
            float s = cs[q * 32 + e]; int gi = ci[q * 32 + e];
            INS8(s, gi);
        }
        float m = ts[0];
        float w[8]; float sum = 0.f;
#pragma unroll
        for (int r = 0; r < 8; ++r) { w[r] = expf(ts[r] - m); sum += w[r]; }
        float rs = 1.0f / sum;
#pragma unroll
        for (int r = 0; r < 8; ++r) {
            fi[r] = ti[r];
            wr[r] = w[r] * rs;
            out[BATCH * EMBED + q * TOPK + r] = ts[r];
            out[BATCH * EMBED + BATCH * TOPK + q * TOPK + r] = (float)ti[r];
        }
    }
    __syncthreads();

    int lane = tid & 63, wave = tid >> 6;
    for (int r = wave; r < TOPK; r += 4) {
        const float* dp = docs + (size_t)fi[r] * EMBED;
        float s = 0.f;
#pragma unroll
        for (int i = 0; i < 6; ++i) { float v = dp[lane + 64 * i]; s = fmaf(v, v, s); }
#pragma unroll
        for (int off = 32; off > 0; off >>= 1) s += __shfl_xor(s, off);
        if (lane == 0) wr[r] = wr[r] / (sqrtf(s) + EPSN);
    }
    __syncthreads();

    for (int dim = tid; dim < EMBED; dim += 256) {
        float a = 0.f;
#pragma unroll
        for (int r = 0; r < 8; ++r)
            a += wr[r] * docs[(size_t)fi[r] * EMBED + dim];
        out[q * EMBED + dim] = a;
    }
}

extern "C" void kernel_launch(void* const* d_in, const int* in_sizes, int n_in,
                              void* d_out, int out_size, void* d_ws, size_t ws_size,
                              hipStream_t stream) {
    const float* query = (const float*)d_in[0];
    const float* docs  = (const float*)d_in[1];
    float* out = (float*)d_out;

    char* ws = (char*)d_ws;
    unsigned short* qh = (unsigned short*)ws;                       // 48 KiB
    unsigned short* ql = (unsigned short*)(ws + 49152);             // 48 KiB
    float* pscore = (float*)(ws + 98304);                           // 2 MiB
    int*   pidx   = (int*)(ws + 98304 + (size_t)NBLK * BATCH * TOPK * 4);
    char*  ws3    = ws + 98304 + 2 * (size_t)NBLK * BATCH * TOPK * 4;
    float* cs     = (float*)ws3;                                    // 8 KiB
    int*   ci     = (int*)(ws3 + BATCH * 4 * TOPK * 4);

    qprep_kernel<<<64, 64, 0, stream>>>(query, qh, ql);
    score_topk_kernel<<<NBLK, 256, 0, stream>>>(docs, qh, ql, pscore, pidx);
    merge_a_kernel<<<BATCH * 4, 256, 0, stream>>>(pscore, pidx, cs, ci);
    merge_b_kernel<<<BATCH, 256, 0, stream>>>(docs, cs, ci, out);
}

// Round 7
// 237.571 us; speedup vs baseline: 1.7433x; 1.0056x over previous
//
#include <hip/hip_runtime.h>
#include <math.h>

// NanoRAG: cosine-sim retrieval + top-8 + softmax fusion.
// K0: normalize queries, split into bf16 hi/lo -> ws.qh/ws.ql
// K1: split-bf16 MFMA GEMM, 256 docs/block, 4 waves SPLIT THE Q-DIM:
//     each wave holds its 16-q fragments for ALL k in registers (96 VGPR,
//     loaded once -> q traffic /4). Docs reg-staged coalesced (8x128B
//     segments), RNE-split once, shared via LDS hi/lo tile (stride 80B),
//     2 barriers/iter, loads prefetched one phase ahead, depth-2 ds_read
//     pipeline with counted lgkmcnt. Inline doc-norm. Per-block top-8.
// K2a: partial merge 1024 lists -> 4 chunk lists per q (256 blocks)
// K2b: final merge 32 -> top-8, softmax, gather+fuse -> d_out
//
// d_out layout (fp32): fused[64*384], scores[64*8], idx[64*8]

#define EMBED 384
#define NDOCS 262144
#define BATCH 64
#define TOPK 8
#define DBLK 256
#define NBLK (NDOCS / DBLK)   // 1024
#define EPSN 1e-8f
#define SCW 260               // score tile stride (words)
#define LO_OFF 20480u         // lo-plane LDS byte offset (256 rows * 80 B)
#define RN_OFF 66560          // rnorm LDS byte offset (after 64x260 S tile)

typedef __attribute__((ext_vector_type(8))) short bf16x8;
typedef __attribute__((ext_vector_type(4))) float f32x4;

// register-resident sorted top-8 insertion (all indices compile-time)
#define INS8(s_, i_) do {                                                     \
    if ((s_) > ts[7] || ((s_) == ts[7] && (i_) < ti[7])) {                    \
        ts[7] = (s_); ti[7] = (i_);                                           \
        _Pragma("unroll")                                                     \
        for (int r_ = 7; r_ > 0; --r_) {                                      \
            bool sw_ = (ts[r_] > ts[r_-1]) ||                                 \
                       (ts[r_] == ts[r_-1] && ti[r_] < ti[r_-1]);             \
            float a_ = ts[r_-1]; int b_ = ti[r_-1];                           \
            ts[r_-1] = sw_ ? ts[r_] : a_;  ti[r_-1] = sw_ ? ti[r_] : b_;      \
            ts[r_]   = sw_ ? a_ : ts[r_];  ti[r_]   = sw_ ? b_ : ti[r_];      \
        }                                                                     \
    }                                                                         \
} while (0)

// saddr-form global load: 32-bit per-lane voffset + uniform SGPR base
template<int OFF>
__device__ __forceinline__ int4 gload_s(unsigned voff, const void* sbase) {
    int4 r;
    asm volatile("global_load_dwordx4 %0, %1, %2 offset:%3"
                 : "=v"(r) : "v"(voff), "s"(sbase), "i"(OFF) : "memory");
    return r;
}

__device__ __forceinline__ int4 dsread16(unsigned a) {
    int4 r;
    asm volatile("ds_read_b128 %0, %1" : "=v"(r) : "v"(a) : "memory");
    return r;
}

// Manual RNE bf16 split: f ~= hi + lo, |err| <= 2^-18|f|. PROVEN numerics
// (R2/R3/R6 absmax 3e-5). Do NOT use v_cvt_pk_bf16_f32 (R4 index flip).
#define SPB(F, H, O) {                                                        \
    unsigned u_ = __float_as_uint(F);                                         \
    H = (u_ + 0x7fffu + ((u_ >> 16) & 1u)) >> 16;                             \
    float r_ = (F) - __uint_as_float((H) << 16);                              \
    unsigned v_ = __float_as_uint(r_);                                        \
    O = (v_ + 0x7fffu + ((v_ >> 16) & 1u)) >> 16;                             \
}

// split chunk J (4 floats) -> packed hi/lo uint2 + sumsq accumulate
#define SPLIT4(J) {                                                           \
    f32x4 f_ = *(f32x4*)&ld[J];                                               \
    nacc[J] = fmaf(f_[0], f_[0], fmaf(f_[1], f_[1],                           \
              fmaf(f_[2], f_[2], fmaf(f_[3], f_[3], nacc[J]))));              \
    unsigned h0_, h1_, h2_, h3_, o0_, o1_, o2_, o3_;                          \
    SPB(f_[0], h0_, o0_); SPB(f_[1], h1_, o1_);                               \
    SPB(f_[2], h2_, o2_); SPB(f_[3], h3_, o3_);                               \
    sh[J].x = (h0_ & 0xffffu) | (h1_ << 16);                                  \
    sh[J].y = (h2_ & 0xffffu) | (h3_ << 16);                                  \
    sl[J].x = (o0_ & 0xffffu) | (o1_ << 16);                                  \
    sl[J].y = (o2_ & 0xffffu) | (o3_ << 16);                                  \
}

__global__ void qprep_kernel(const float* __restrict__ q,
                             unsigned short* __restrict__ qh,
                             unsigned short* __restrict__ ql) {
    const int row = blockIdx.x;     // 64 blocks
    const int lane = threadIdx.x;   // 64 threads
    float v[6];
    float s = 0.f;
#pragma unroll
    for (int i = 0; i < 6; ++i) {
        v[i] = q[row * EMBED + lane + 64 * i];
        s = fmaf(v[i], v[i], s);
    }
#pragma unroll
    for (int off = 32; off > 0; off >>= 1) s += __shfl_xor(s, off);
    float rinv = 1.0f / (sqrtf(s) + EPSN);
#pragma unroll
    for (int i = 0; i < 6; ++i) {
        float f = v[i] * rinv;
        unsigned h, lo;
        SPB(f, h, lo);
        qh[row * EMBED + lane + 64 * i] = (unsigned short)h;
        ql[row * EMBED + lane + 64 * i] = (unsigned short)lo;
    }
}

__global__ __launch_bounds__(256, 2) void score_topk_kernel(
        const float* __restrict__ docs,
        const unsigned short* __restrict__ qh,
        const unsigned short* __restrict__ ql,
        float* __restrict__ pscore, int* __restrict__ pidx) {
    // LDS: k-loop: hi-plane [0,20480) + lo-plane [20480,40960), 256 rows
    // stride 80 B. Epilogue overlays S[64][260] @0; RN[256] @66560.
    __shared__ __align__(16) char smem[67584];
    float* S  = (float*)smem;
    float* RN = (float*)(smem + RN_OFF);

    const int tid = threadIdx.x;
    const int l   = tid & 63;
    const int wv  = tid >> 6;          // wave -> q-tile wv, doc-quarter wv
    const int rowl = l & 15;
    const int ksub = l >> 4;
    const int d0 = blockIdx.x * DBLK;
    const unsigned bse = (unsigned)(uintptr_t)smem;

    f32x4 acc[16];                     // 16 q x 256 docs
#pragma unroll
    for (int s = 0; s < 16; ++s) acc[s] = (f32x4){0.f, 0.f, 0.f, 0.f};
    float nacc[8];
#pragma unroll
    for (int j = 0; j < 8; ++j) nacc[j] = 0.f;

    // ---- q fragments: this wave's 16 q rows, ALL 384 k, in registers ----
    int4 qf[12][2];
    {
        unsigned vq = (unsigned)((wv * 16 + rowl) * (EMBED * 2) + ksub * 16);
#pragma unroll
        for (int kb = 0; kb < 12; ++kb) {
            qf[kb][0] = gload_s<0>(vq, qh);
            qf[kb][1] = gload_s<0>(vq, ql);
            vq += 64;
        }
    }

    // doc voffsets: chunk j = rows wv*64 + j*8 + (l>>3), bytes (l&7)*16
    unsigned voff[8];
#pragma unroll
    for (int j = 0; j < 8; ++j)
        voff[j] = (unsigned)((d0 + wv * 64 + j * 8 + (l >> 3)) * 1536u)
                + (unsigned)((l & 7) * 16);

    int4 ld[8];
#pragma unroll
    for (int j = 0; j < 8; ++j) ld[j] = gload_s<0>(voff[j], docs);

    uint2 sh[8], sl[8];
    asm volatile("s_waitcnt vmcnt(0)" ::: "memory");
    __builtin_amdgcn_sched_barrier(0);
#pragma unroll
    for (int j = 0; j < 8; ++j) SPLIT4(j);

    const unsigned wbase = wv * 5120u + (unsigned)((l >> 3) * 80 + (l & 7) * 8);
    const unsigned rbase = (unsigned)(rowl * 80 + ksub * 16);

#define KITER(KB, LAST) {                                                      \
    __syncthreads();                       /* prior tile reads done */         \
    _Pragma("unroll")                                                          \
    for (int j = 0; j < 8; ++j) {                                              \
        *(uint2*)(smem + wbase + j * 640u) = sh[j];                            \
        *(uint2*)(smem + LO_OFF + wbase + j * 640u) = sl[j];                   \
    }                                                                          \
    __syncthreads();                       /* tile KB ready */                 \
    if (!(LAST)) {                                                             \
        _Pragma("unroll")                                                      \
        for (int j = 0; j < 8; ++j)                                            \
            ld[j] = gload_s<((KB) + 1) * 128>(voff[j], docs);                  \
    }                                                                          \
    {                                                                          \
        int4 fh0, fl0, fh1, fl1;                                               \
        fh0 = dsread16(bse + rbase);                                           \
        fl0 = dsread16(bse + rbase + LO_OFF);                                  \
        _Pragma("unroll")                                                      \
        for (int s = 0; s < 16; ++s) {                                         \
            if (s < 15) {                                                      \
                fh1 = dsread16(bse + rbase + (unsigned)((s + 1) * 1280));      \
                fl1 = dsread16(bse + rbase + (unsigned)((s + 1) * 1280) + LO_OFF); \
                asm volatile("s_waitcnt lgkmcnt(2)" ::: "memory");             \
            } else {                                                           \
                asm volatile("s_waitcnt lgkmcnt(0)" ::: "memory");             \
            }                                                                  \
            __builtin_amdgcn_sched_barrier(0);                                 \
            bf16x8 bh = *(bf16x8*)&fh0, bl = *(bf16x8*)&fl0;                   \
            bf16x8 ah = *(bf16x8*)&qf[KB][0], al = *(bf16x8*)&qf[KB][1];       \
            acc[s] = __builtin_amdgcn_mfma_f32_16x16x32_bf16(ah, bh, acc[s], 0, 0, 0); \
            acc[s] = __builtin_amdgcn_mfma_f32_16x16x32_bf16(al, bh, acc[s], 0, 0, 0); \
            acc[s] = __builtin_amdgcn_mfma_f32_16x16x32_bf16(ah, bl, acc[s], 0, 0, 0); \
            fh0 = fh1; fl0 = fl1;                                              \
        }                                                                      \
    }                                                                          \
    if (!(LAST)) {                                                             \
        asm volatile("s_waitcnt vmcnt(0)" ::: "memory");                       \
        __builtin_amdgcn_sched_barrier(0);                                     \
        _Pragma("unroll")                                                      \
        for (int j = 0; j < 8; ++j) SPLIT4(j);                                 \
    }                                                                          \
}

    KITER(0, 0)  KITER(1, 0)  KITER(2, 0)  KITER(3, 0)
    KITER(4, 0)  KITER(5, 0)  KITER(6, 0)  KITER(7, 0)
    KITER(8, 0)  KITER(9, 0)  KITER(10, 0) KITER(11, 1)
#undef KITER

    // doc norms: octet xor-reduce of per-lane partials (once, not per iter)
#pragma unroll
    for (int j = 0; j < 8; ++j) {
        float t = nacc[j];
        t += __shfl_xor(t, 1);
        t += __shfl_xor(t, 2);
        t += __shfl_xor(t, 4);
        if ((l & 7) == 0)
            RN[wv * 64 + j * 8 + (l >> 3)] = 1.0f / (sqrtf(t) + EPSN);
    }
    __syncthreads();   // all MFMA reads of hi/lo done + RN visible

    // park normalized scores: q = wv*16 + ksub*4 + jj, doc col = s*16 + rowl
#pragma unroll
    for (int s = 0; s < 16; ++s) {
        float rn = RN[s * 16 + rowl];
#pragma unroll
        for (int jj = 0; jj < 4; ++jj)
            S[(wv * 16 + ksub * 4 + jj) * SCW + s * 16 + rowl] = acc[s][jj] * rn;
    }
    __syncthreads();

    // top-8: thread t scans query t&63 over quarter (t>>6)*64..+63, staggered
    float ts[8]; int ti[8];
#pragma unroll
    for (int r = 0; r < 8; ++r) { ts[r] = -3.402823466e38f; ti[r] = 0x7fffffff; }
    const int q = tid & 63, qa = tid >> 6;
    for (int ii = 0; ii < 64; ++ii) {
        int d = qa * 64 + ((ii + q) & 63);
        float sc = S[q * SCW + d];
        INS8(sc, d0 + d);
    }
    __syncthreads();   // all S reads done; safe to overwrite
#pragma unroll
    for (int r = 0; r < 8; ++r) {
        S[(qa * 64 + q) * 8 + r] = ts[r];
        S[2048 + (qa * 64 + q) * 8 + r] = __int_as_float(ti[r]);
    }
    __syncthreads();
    if (tid < 64) {
#pragma unroll
        for (int r = 0; r < 8; ++r) { ts[r] = -3.402823466e38f; ti[r] = 0x7fffffff; }
        for (int a = 0; a < 4; ++a) {
#pragma unroll
            for (int r = 0; r < 8; ++r) {
                float s2 = S[(a * 64 + q) * 8 + r];
                int i2 = __float_as_int(S[2048 + (a * 64 + q) * 8 + r]);
                INS8(s2, i2);
            }
        }
        size_t o = ((size_t)q * NBLK + blockIdx.x) * TOPK;
        *(float4*)&pscore[o]     = make_float4(ts[0], ts[1], ts[2], ts[3]);
        *(float4*)&pscore[o + 4] = make_float4(ts[4], ts[5], ts[6], ts[7]);
        *(int4*)&pidx[o]     = make_int4(ti[0], ti[1], ti[2], ti[3]);
        *(int4*)&pidx[o + 4] = make_int4(ti[4], ti[5], ti[6], ti[7]);
    }
}

// stage A: block (q, c) merges lists c*256..c*256+255 -> one top-8 chunk list
__global__ __launch_bounds__(256) void merge_a_kernel(
        const float* __restrict__ pscore, const int* __restrict__ pidx,
        float* __restrict__ cs, int* __restrict__ ci) {
    const int q = blockIdx.x >> 2;
    const int c = blockIdx.x & 3;
    const int tid = threadIdx.x;
    __shared__ float ls[2048];
    __shared__ int   li[2048];
    __shared__ float ls2[512];
    __shared__ int   li2[512];
    __shared__ float ls3[64];
    __shared__ int   li3[64];

    {
        size_t o = ((size_t)q * NBLK + c * 256 + tid) * TOPK;
        float4 s0 = *(const float4*)&pscore[o];
        float4 s1 = *(const float4*)&pscore[o + 4];
        int4 i0 = *(const int4*)&pidx[o];
        int4 i1 = *(const int4*)&pidx[o + 4];
        ls[tid * 8 + 0] = s0.x; ls[tid * 8 + 1] = s0.y;
        ls[tid * 8 + 2] = s0.z; ls[tid * 8 + 3] = s0.w;
        ls[tid * 8 + 4] = s1.x; ls[tid * 8 + 5] = s1.y;
        ls[tid * 8 + 6] = s1.z; ls[tid * 8 + 7] = s1.w;
        li[tid * 8 + 0] = i0.x; li[tid * 8 + 1] = i0.y;
        li[tid * 8 + 2] = i0.z; li[tid * 8 + 3] = i0.w;
        li[tid * 8 + 4] = i1.x; li[tid * 8 + 5] = i1.y;
        li[tid * 8 + 6] = i1.z; li[tid * 8 + 7] = i1.w;
    }
    __syncthreads();

    float ts[8]; int ti[8];
    if (tid < 64) {
#pragma unroll
        for (int r = 0; r < 8; ++r) { ts[r] = -3.402823466e38f; ti[r] = 0x7fffffff; }
        for (int e = 0; e < 32; ++e) {
            int k = tid + e * 64;
            float s = ls[k]; int gi = li[k];
            INS8(s, gi);
        }
#pragma unroll
        for (int r = 0; r < 8; ++r) { ls2[tid * 8 + r] = ts[r]; li2[tid * 8 + r] = ti[r]; }
    }
    __syncthreads();
    if (tid < 8) {
#pragma unroll
        for (int r = 0; r < 8; ++r) { ts[r] = -3.402823466e38f; ti[r] = 0x7fffffff; }
        for (int e = 0; e < 64; ++e) {
            int k = tid + e * 8;
            float s = ls2[k]; int gi = li2[k];
            INS8(s, gi);
        }
#pragma unroll
        for (int r = 0; r < 8; ++r) { ls3[tid * 8 + r] = ts[r]; li3[tid * 8 + r] = ti[r]; }
    }
    __syncthreads();
    if (tid == 0) {
#pragma unroll
        for (int r = 0; r < 8; ++r) { ts[r] = -3.402823466e38f; ti[r] = 0x7fffffff; }
        for (int e = 0; e < 64; ++e) {
            float s = ls3[e]; int gi = li3[e];
            INS8(s, gi);
        }
        size_t o = (size_t)(q * 4 + c) * TOPK;
#pragma unroll
        for (int r = 0; r < 8; ++r) { cs[o + r] = ts[r]; ci[o + r] = ti[r]; }
    }
}

// stage B: final merge (32 candidates), softmax, gather+fuse
__global__ __launch_bounds__(256) void merge_b_kernel(
        const float* __restrict__ docs, const float* __restrict__ cs,
        const int* __restrict__ ci, float* __restrict__ out) {
    const int q = blockIdx.x;
    const int tid = threadIdx.x;
    __shared__ int   fi[TOPK];
    __shared__ float wr[TOPK];

    if (tid == 0) {
        float ts[8]; int ti[8];
#pragma unroll
        for (int r = 0; r < 8; ++r) { ts[r] = -3.402823466e38f; ti[r] = 0x7fffffff; }
        for (int e = 0; e < 32; ++e) {
            float s = cs[q * 32 + e]; int gi = ci[q * 32 + e];
            INS8(s, gi);
        }
        float m = ts[0];
        float w[8]; float sum = 0.f;
#pragma unroll
        for (int r = 0; r < 8; ++r) { w[r] = expf(ts[r] - m); sum += w[r]; }
        float rs = 1.0f / sum;
#pragma unroll
        for (int r = 0; r < 8; ++r) {
            fi[r] = ti[r];
            wr[r] = w[r] * rs;
            out[BATCH * EMBED + q * TOPK + r] = ts[r];
            out[BATCH * EMBED + BATCH * TOPK + q * TOPK + r] = (float)ti[r];
        }
    }
    __syncthreads();

    int lane = tid & 63, wave = tid >> 6;
    for (int r = wave; r < TOPK; r += 4) {
        const float* dp = docs + (size_t)fi[r] * EMBED;
        float s = 0.f;
#pragma unroll
        for (int i = 0; i < 6; ++i) { float v = dp[lane + 64 * i]; s = fmaf(v, v, s); }
#pragma unroll
        for (int off = 32; off > 0; off >>= 1) s += __shfl_xor(s, off);
        if (lane == 0) wr[r] = wr[r] / (sqrtf(s) + EPSN);
    }
    __syncthreads();

    for (int dim = tid; dim < EMBED; dim += 256) {
        float a = 0.f;
#pragma unroll
        for (int r = 0; r < 8; ++r)
            a += wr[r] * docs[(size_t)fi[r] * EMBED + dim];
        out[q * EMBED + dim] = a;
    }
}

extern "C" void kernel_launch(void* const* d_in, const int* in_sizes, int n_in,
                              void* d_out, int out_size, void* d_ws, size_t ws_size,
                              hipStream_t stream) {
    const float* query = (const float*)d_in[0];
    const float* docs  = (const float*)d_in[1];
    float* out = (float*)d_out;

    char* ws = (char*)d_ws;
    unsigned short* qh = (unsigned short*)ws;                       // 48 KiB
    unsigned short* ql = (unsigned short*)(ws + 49152);             // 48 KiB
    float* pscore = (float*)(ws + 98304);                           // 2 MiB
    int*   pidx   = (int*)(ws + 98304 + (size_t)NBLK * BATCH * TOPK * 4);
    char*  ws3    = ws + 98304 + 2 * (size_t)NBLK * BATCH * TOPK * 4;
    float* cs     = (float*)ws3;                                    // 8 KiB
    int*   ci     = (int*)(ws3 + BATCH * 4 * TOPK * 4);

    qprep_kernel<<<64, 64, 0, stream>>>(query, qh, ql);
    score_topk_kernel<<<NBLK, 256, 0, stream>>>(docs, qh, ql, pscore, pidx);
    merge_a_kernel<<<BATCH * 4, 256, 0, stream>>>(pscore, pidx, cs, ci);
    merge_b_kernel<<<BATCH, 256, 0, stream>>>(docs, cs, ci, out);
}